// Round 1
// baseline (219.934 us; speedup 1.0000x reference)
//
#include <hip/hip_runtime.h>
#include <math.h>
#include <cstdint>
#include <cstddef>

typedef unsigned short u16;
typedef short bf16x8 __attribute__((ext_vector_type(8)));
typedef float f32x4 __attribute__((ext_vector_type(4)));
typedef u16 u16x8 __attribute__((ext_vector_type(8)));
typedef u16 u16x4 __attribute__((ext_vector_type(4)));

#define T_LEN 4096
#define NH 12
#define HD 64
#define DMODEL 768
#define GK 768                    // K dim for both GEMMs
#define QKV_STRIDE 6291456ul      // elements per q/k/v tensor = 2*12*4096*64

__device__ __forceinline__ u16 f2bf(float x) {
  union { float f; unsigned u; } v; v.f = x;
  unsigned r = v.u + 0x7fffu + ((v.u >> 16) & 1u);
  return (u16)(r >> 16);
}
__device__ __forceinline__ float bf2f(u16 x) {
  union { unsigned u; float f; } v; v.u = ((unsigned)x) << 16;
  return v.f;
}

// async global->LDS, 16B per lane. LDS dest is wave-uniform base + lane*16.
__device__ __forceinline__ void async16(const u16* g, u16* l) {
  __builtin_amdgcn_global_load_lds(
      (const __attribute__((address_space(1))) unsigned int*)g,
      (__attribute__((address_space(3))) unsigned int*)l, 16, 0, 0);
}

// ---------------- fp32 -> bf16 conversion ----------------
__global__ void cvt_f32_bf16(const float* __restrict__ s, u16* __restrict__ d, int n) {
  int i = (blockIdx.x * blockDim.x + threadIdx.x) * 4;
  if (i >= n) return;
  float4 v = *(const float4*)(s + i);
  u16x4 o;
  o[0] = f2bf(v.x); o[1] = f2bf(v.y); o[2] = f2bf(v.z); o[3] = f2bf(v.w);
  *(u16x4*)(d + i) = o;
}

// ---------------- GEMM: C = A[M,K] * B[N,K]^T + bias ----------------
// 128x128 tile, BK=32, 256 threads (4 waves, 2x2 of 64x64), 16x16x32 bf16 MFMA.
// EPI=0: out cols are concat(q,k,v); scatter bf16 into qkv[3][B][H][T][D], bias (bq,bk,bv)
// EPI=1: plain fp32 row-major out [M,768] + bias0
#define BM 128
#define BN 128
#define BK 32

template <int EPI>
__global__ __launch_bounds__(256)
void gemm_bt(const u16* __restrict__ A, const u16* __restrict__ B,
             const float* __restrict__ bias0, const float* __restrict__ bias1,
             const float* __restrict__ bias2, void* __restrict__ outp) {
  __shared__ __align__(16) u16 As[BM * BK];
  __shared__ __align__(16) u16 Bs[BN * BK];
  const int tid  = threadIdx.x;
  const int lane = tid & 63;
  const int wave = tid >> 6;
  const int wm = wave & 1, wn = wave >> 1;
  const long am0 = (long)blockIdx.x * BM;
  const long bn0 = (long)blockIdx.y * BN;
  const int r16 = lane & 15;   // fragment row (m or n) within 16
  const int kh  = lane >> 4;   // k-chunk 0..3 (8 elems each)

  f32x4 acc[4][4] = {};

  // staging: wave w loads 16 rows at w*16 and 64+w*16 (A and B), lane -> (row lane>>2, kchunk lane&3)
  const int srow = lane >> 2;
  const int skc  = (lane & 3) * 8;
  const u16* Ag = A + (am0 + wave * 16 + srow) * GK + skc;
  const u16* Bg = B + (bn0 + wave * 16 + srow) * GK + skc;
  u16* Al0 = &As[(wave * 16) * BK];
  u16* Al1 = &As[(64 + wave * 16) * BK];
  u16* Bl0 = &Bs[(wave * 16) * BK];
  u16* Bl1 = &Bs[(64 + wave * 16) * BK];

  for (int kt = 0; kt < GK; kt += BK) {
    __syncthreads();
    async16(Ag + kt, Al0);
    async16(Ag + 64 * GK + kt, Al1);
    async16(Bg + kt, Bl0);
    async16(Bg + 64 * GK + kt, Bl1);
    __syncthreads();
    bf16x8 af[4], bfr[4];
#pragma unroll
    for (int i = 0; i < 4; i++)
      af[i] = *(const bf16x8*)&As[(wm * 64 + i * 16 + r16) * BK + kh * 8];
#pragma unroll
    for (int j = 0; j < 4; j++)
      bfr[j] = *(const bf16x8*)&Bs[(wn * 64 + j * 16 + r16) * BK + kh * 8];
#pragma unroll
    for (int i = 0; i < 4; i++)
#pragma unroll
      for (int j = 0; j < 4; j++)
        acc[i][j] = __builtin_amdgcn_mfma_f32_16x16x32_bf16(af[i], bfr[j], acc[i][j], 0, 0, 0);
  }

  const int m0 = (int)am0 + wm * 64;
  const int n0 = (int)bn0 + wn * 64;
  if (EPI == 0) {
    u16* qkv = (u16*)outp;
#pragma unroll
    for (int j = 0; j < 4; j++) {
      int col = n0 + j * 16 + r16;          // 0..2303
      int tens = col / 768;
      int c = col - tens * 768;
      const float* bp = (tens == 0) ? bias0 : ((tens == 1) ? bias1 : bias2);
      float bv = bp[c];
      int hh = c >> 6, dd = c & 63;
#pragma unroll
      for (int i = 0; i < 4; i++) {
#pragma unroll
        for (int r = 0; r < 4; r++) {
          int row = m0 + i * 16 + kh * 4 + r;   // b*T + t
          int b_ = row >> 12, t = row & 4095;
          size_t off = (size_t)tens * QKV_STRIDE +
                       ((((size_t)(b_ * NH + hh)) * T_LEN + t) << 6) + dd;
          qkv[off] = f2bf(acc[i][j][r] + bv);
        }
      }
    }
  } else {
    float* O = (float*)outp;
#pragma unroll
    for (int i = 0; i < 4; i++) {
#pragma unroll
      for (int r = 0; r < 4; r++) {
        int row = m0 + i * 16 + kh * 4 + r;
        float* orow = O + (size_t)row * DMODEL;
#pragma unroll
        for (int j = 0; j < 4; j++) {
          int col = n0 + j * 16 + r16;
          orow[col] = acc[i][j][r] + bias0[col];
        }
      }
    }
  }
}

// ---------------- banded local attention ----------------
// 128 queries/block (128 threads, 1 query each). K/V slab rows [q0-16, q0+143] in LDS.
// K as fp32 (row pad 66 -> 8B-aligned float2 reads, conflict-free), V as bf16 (row pad 72, 16B aligned).
#define QB 128
#define SLAB 160

__global__ __launch_bounds__(128)
void attn_local(const u16* __restrict__ qkv, u16* __restrict__ attn) {
  __shared__ __align__(16) float Ks[SLAB][66];  // 42240 B
  __shared__ __align__(16) u16 Vs[SLAB][72];    // 23040 B  (total 65280 <= 64KB)
  const int tid = threadIdx.x;
  const int q0 = blockIdx.x * QB;
  const int h = blockIdx.y, b = blockIdx.z;
  const size_t head = ((size_t)(b * NH + h)) * (T_LEN * HD);
  const u16* Qg = qkv + head;
  const u16* Kg = qkv + QKV_STRIDE + head;
  const u16* Vg = qkv + 2 * QKV_STRIDE + head;

  // cooperative slab load: 160 rows x 64 elems, 8-elem chunks
  for (int e = tid; e < SLAB * 8; e += QB) {
    int r = e >> 3, c8 = (e & 7) * 8;
    int g = q0 - 16 + r;
    if (g >= 0 && g < T_LEN) {
      u16x8 kv = *(const u16x8*)(Kg + (size_t)g * HD + c8);
      u16x8 vv = *(const u16x8*)(Vg + (size_t)g * HD + c8);
#pragma unroll
      for (int z = 0; z < 8; z++) Ks[r][c8 + z] = bf2f(kv[z]);
      *(u16x8*)&Vs[r][c8] = vv;
    } else {
#pragma unroll
      for (int z = 0; z < 8; z++) Ks[r][c8 + z] = 0.f;
      u16x8 zz = {0, 0, 0, 0, 0, 0, 0, 0};
      *(u16x8*)&Vs[r][c8] = zz;
    }
  }

  const int t = q0 + tid;
  float q[64];
#pragma unroll
  for (int c8 = 0; c8 < 64; c8 += 8) {
    u16x8 qv = *(const u16x8*)(Qg + (size_t)t * HD + c8);
#pragma unroll
    for (int z = 0; z < 8; z++) q[c8 + z] = bf2f(qv[z]);
  }
  __syncthreads();

  float s[33];
#pragma unroll
  for (int j = 0; j < 33; j++) {
    const float2* kr = (const float2*)&Ks[tid + j][0];
    float a0 = 0.f, a1 = 0.f;
#pragma unroll
    for (int d2 = 0; d2 < 32; d2++) {
      float2 kk = kr[d2];
      a0 += q[2 * d2] * kk.x;
      a1 += q[2 * d2 + 1] * kk.y;
    }
    int kidx = t - 16 + j;
    s[j] = (kidx >= 0 && kidx < T_LEN) ? (a0 + a1) * 0.125f : -INFINITY;
  }
  float m = s[0];
#pragma unroll
  for (int j = 1; j < 33; j++) m = fmaxf(m, s[j]);
  float l = 0.f;
#pragma unroll
  for (int j = 0; j < 33; j++) {
    float p = __expf(s[j] - m);
    s[j] = p;
    l += p;
  }
  float inv = 1.0f / l;

  float o[64] = {};
#pragma unroll
  for (int j = 0; j < 33; j++) {
    float p = s[j];
    const u16* vr = &Vs[tid + j][0];
#pragma unroll
    for (int c8 = 0; c8 < 64; c8 += 8) {
      u16x8 vv = *(const u16x8*)(vr + c8);
#pragma unroll
      for (int z = 0; z < 8; z++) o[c8 + z] += p * bf2f(vv[z]);
    }
  }

  u16* orow = attn + ((size_t)(b * T_LEN + t)) * DMODEL + h * HD;
#pragma unroll
  for (int c8 = 0; c8 < 64; c8 += 8) {
    u16x8 ov;
#pragma unroll
    for (int z = 0; z < 8; z++) ov[z] = f2bf(o[c8 + z] * inv);
    *(u16x8*)(orow + c8) = ov;
  }
}

// ---------------- launch ----------------
extern "C" void kernel_launch(void* const* d_in, const int* in_sizes, int n_in,
                              void* d_out, int out_size, void* d_ws, size_t ws_size,
                              hipStream_t stream) {
  const float* x  = (const float*)d_in[0];
  const float* Wq = (const float*)d_in[1];
  const float* bq = (const float*)d_in[2];
  const float* Wk = (const float*)d_in[3];
  const float* bk = (const float*)d_in[4];
  const float* Wv = (const float*)d_in[5];
  const float* bv = (const float*)d_in[6];
  const float* Wo = (const float*)d_in[7];
  const float* bo = (const float*)d_in[8];
  float* out = (float*)d_out;
  char* ws = (char*)d_ws;

  // ws layout (bytes, all 256-aligned):
  u16* xb   = (u16*)(ws);                 // 8192*768 bf16       = 12,582,912 B
  u16* wqkv = (u16*)(ws + 12582912);      // 2304*768 bf16       =  3,538,944 B
  u16* wo_b = (u16*)(ws + 16121856);      // 768*768 bf16        =  1,179,648 B
  u16* qkv  = (u16*)(ws + 17301504);      // 3*6291456 bf16      = 37,748,736 B
  u16* attn = (u16*)(ws + 55050240);      // 8192*768 bf16       = 12,582,912 B
                                          // total               = 67,633,152 B

  cvt_f32_bf16<<<6144, 256, 0, stream>>>(x, xb, 6291456);
  cvt_f32_bf16<<<576, 256, 0, stream>>>(Wq, wqkv, 589824);
  cvt_f32_bf16<<<576, 256, 0, stream>>>(Wk, wqkv + 589824, 589824);
  cvt_f32_bf16<<<576, 256, 0, stream>>>(Wv, wqkv + 1179648, 589824);
  cvt_f32_bf16<<<576, 256, 0, stream>>>(Wo, wo_b, 589824);

  gemm_bt<0><<<dim3(64, 18), 256, 0, stream>>>(xb, wqkv, bq, bk, bv, (void*)qkv);
  attn_local<<<dim3(32, 12, 2), 128, 0, stream>>>(qkv, attn);
  gemm_bt<1><<<dim3(64, 6), 256, 0, stream>>>(attn, wo_b, bo, bo, bo, (void*)out);
}

// Round 2
// 189.182 us; speedup vs baseline: 1.1626x; 1.1626x over previous
//
#include <hip/hip_runtime.h>
#include <math.h>
#include <cstdint>
#include <cstddef>

typedef unsigned short u16;
typedef short bf16x8 __attribute__((ext_vector_type(8)));
typedef float f32x4 __attribute__((ext_vector_type(4)));
typedef u16 u16x8 __attribute__((ext_vector_type(8)));
typedef u16 u16x4 __attribute__((ext_vector_type(4)));

#define T_LEN 4096
#define NH 12
#define HD 64
#define DMODEL 768
#define GK 768                    // K dim for both GEMMs
#define QKV_STRIDE 6291456ul      // elements per q/k/v tensor = 2*12*4096*64

__device__ __forceinline__ u16 f2bf(float x) {
  union { float f; unsigned u; } v; v.f = x;
  unsigned r = v.u + 0x7fffu + ((v.u >> 16) & 1u);
  return (u16)(r >> 16);
}
__device__ __forceinline__ float bf2f(u16 x) {
  union { unsigned u; float f; } v; v.u = ((unsigned)x) << 16;
  return v.f;
}
// unpack packed bf16 pair (u32) -> (lo, hi) floats
__device__ __forceinline__ void bfpair(unsigned u, float& lo, float& hi) {
  union { unsigned u; float f; } a, b;
  a.u = u << 16; b.u = u & 0xffff0000u;
  lo = a.f; hi = b.f;
}

// async global->LDS, 16B per lane. LDS dest is wave-uniform base + lane*16.
__device__ __forceinline__ void async16(const u16* g, u16* l) {
  __builtin_amdgcn_global_load_lds(
      (const __attribute__((address_space(1))) unsigned int*)g,
      (__attribute__((address_space(3))) unsigned int*)l, 16, 0, 0);
}

// ---------------- fp32 -> bf16 conversion ----------------
__global__ void cvt_f32_bf16(const float* __restrict__ s, u16* __restrict__ d, int n) {
  int i = (blockIdx.x * blockDim.x + threadIdx.x) * 4;
  if (i >= n) return;
  float4 v = *(const float4*)(s + i);
  u16x4 o;
  o[0] = f2bf(v.x); o[1] = f2bf(v.y); o[2] = f2bf(v.z); o[3] = f2bf(v.w);
  *(u16x4*)(d + i) = o;
}

// 4 weight tensors (each 589824 elems) in one launch; blockIdx.y selects tensor
__global__ void cvt_w4(const float* __restrict__ s0, const float* __restrict__ s1,
                       const float* __restrict__ s2, const float* __restrict__ s3,
                       u16* __restrict__ d0, u16* __restrict__ d1,
                       u16* __restrict__ d2, u16* __restrict__ d3) {
  const float* s; u16* d;
  switch (blockIdx.y) {
    case 0: s = s0; d = d0; break;
    case 1: s = s1; d = d1; break;
    case 2: s = s2; d = d2; break;
    default: s = s3; d = d3; break;
  }
  int i = (blockIdx.x * blockDim.x + threadIdx.x) * 4;
  float4 v = *(const float4*)(s + i);
  u16x4 o;
  o[0] = f2bf(v.x); o[1] = f2bf(v.y); o[2] = f2bf(v.z); o[3] = f2bf(v.w);
  *(u16x4*)(d + i) = o;
}

// ---------------- GEMM: C = A[M,K] * B[N,K]^T + bias ----------------
#define BM 128
#define BN 128
#define BK 32

template <int EPI>
__global__ __launch_bounds__(256)
void gemm_bt(const u16* __restrict__ A, const u16* __restrict__ B,
             const float* __restrict__ bias0, const float* __restrict__ bias1,
             const float* __restrict__ bias2, void* __restrict__ outp) {
  __shared__ __align__(16) u16 As[BM * BK];
  __shared__ __align__(16) u16 Bs[BN * BK];
  const int tid  = threadIdx.x;
  const int lane = tid & 63;
  const int wave = tid >> 6;
  const int wm = wave & 1, wn = wave >> 1;
  const long am0 = (long)blockIdx.x * BM;
  const long bn0 = (long)blockIdx.y * BN;
  const int r16 = lane & 15;
  const int kh  = lane >> 4;

  f32x4 acc[4][4] = {};

  const int srow = lane >> 2;
  const int skc  = (lane & 3) * 8;
  const u16* Ag = A + (am0 + wave * 16 + srow) * GK + skc;
  const u16* Bg = B + (bn0 + wave * 16 + srow) * GK + skc;
  u16* Al0 = &As[(wave * 16) * BK];
  u16* Al1 = &As[(64 + wave * 16) * BK];
  u16* Bl0 = &Bs[(wave * 16) * BK];
  u16* Bl1 = &Bs[(64 + wave * 16) * BK];

  for (int kt = 0; kt < GK; kt += BK) {
    __syncthreads();
    async16(Ag + kt, Al0);
    async16(Ag + 64 * GK + kt, Al1);
    async16(Bg + kt, Bl0);
    async16(Bg + 64 * GK + kt, Bl1);
    __syncthreads();
    bf16x8 af[4], bfr[4];
#pragma unroll
    for (int i = 0; i < 4; i++)
      af[i] = *(const bf16x8*)&As[(wm * 64 + i * 16 + r16) * BK + kh * 8];
#pragma unroll
    for (int j = 0; j < 4; j++)
      bfr[j] = *(const bf16x8*)&Bs[(wn * 64 + j * 16 + r16) * BK + kh * 8];
#pragma unroll
    for (int i = 0; i < 4; i++)
#pragma unroll
      for (int j = 0; j < 4; j++)
        acc[i][j] = __builtin_amdgcn_mfma_f32_16x16x32_bf16(af[i], bfr[j], acc[i][j], 0, 0, 0);
  }

  const int m0 = (int)am0 + wm * 64;
  const int n0 = (int)bn0 + wn * 64;
  if (EPI == 0) {
    u16* qkv = (u16*)outp;
#pragma unroll
    for (int j = 0; j < 4; j++) {
      int col = n0 + j * 16 + r16;          // 0..2303
      int tens = col / 768;
      int c = col - tens * 768;
      const float* bp = (tens == 0) ? bias0 : ((tens == 1) ? bias1 : bias2);
      float bv = bp[c];
      int hh = c >> 6, dd = c & 63;
#pragma unroll
      for (int i = 0; i < 4; i++) {
#pragma unroll
        for (int r = 0; r < 4; r++) {
          int row = m0 + i * 16 + kh * 4 + r;   // b*T + t
          int b_ = row >> 12, t = row & 4095;
          size_t off = (size_t)tens * QKV_STRIDE +
                       ((((size_t)(b_ * NH + hh)) * T_LEN + t) << 6) + dd;
          qkv[off] = f2bf(acc[i][j][r] + bv);
        }
      }
    }
  } else {
    float* O = (float*)outp;
#pragma unroll
    for (int i = 0; i < 4; i++) {
#pragma unroll
      for (int r = 0; r < 4; r++) {
        int row = m0 + i * 16 + kh * 4 + r;
        float* orow = O + (size_t)row * DMODEL;
#pragma unroll
        for (int j = 0; j < 4; j++) {
          int col = n0 + j * 16 + r16;
          orow[col] = acc[i][j][r] + bias0[col];
        }
      }
    }
  }
}

// ---------------- banded local attention v2 ----------------
// 64 queries/block, 256 threads: 4 threads per query, 16 dims each.
// K,V slabs bf16 in LDS (96 rows x stride 72 = 27648 B total) -> ~5 blocks/CU.
#define QB 64
#define SLAB 96
#define KSTR 72

__global__ __launch_bounds__(256)
void attn_local(const u16* __restrict__ qkv, u16* __restrict__ attn) {
  __shared__ __align__(16) u16 Ks[SLAB][KSTR];
  __shared__ __align__(16) u16 Vs[SLAB][KSTR];
  const int tid = threadIdx.x;
  const int q0 = blockIdx.x * QB;
  const int h = blockIdx.y, b = blockIdx.z;
  const size_t head = ((size_t)(b * NH + h)) * (T_LEN * HD);
  const u16* Qg = qkv + head;
  const u16* Kg = qkv + QKV_STRIDE + head;
  const u16* Vg = qkv + 2 * QKV_STRIDE + head;

  // cooperative slab load: 96 rows x 64 elems in 8-elem chunks = 768 chunks
  for (int e = tid; e < SLAB * 8; e += 256) {
    int r = e >> 3, c8 = (e & 7) * 8;
    int g = q0 - 16 + r;
    if (g >= 0 && g < T_LEN) {
      *(u16x8*)&Ks[r][c8] = *(const u16x8*)(Kg + (size_t)g * HD + c8);
      *(u16x8*)&Vs[r][c8] = *(const u16x8*)(Vg + (size_t)g * HD + c8);
    } else {
      u16x8 zz = {0, 0, 0, 0, 0, 0, 0, 0};
      *(u16x8*)&Ks[r][c8] = zz;
      *(u16x8*)&Vs[r][c8] = zz;
    }
  }

  const int qi = tid >> 2;       // query within block (0..63)
  const int p  = tid & 3;        // dim-part (0..3)
  const int d0 = p * 16;
  const int t  = q0 + qi;

  // load this thread's 16 q dims as fp32
  float qv[16];
  {
    uint4 a = *(const uint4*)(Qg + (size_t)t * HD + d0);
    uint4 bq = *(const uint4*)(Qg + (size_t)t * HD + d0 + 8);
    bfpair(a.x, qv[0], qv[1]);   bfpair(a.y, qv[2], qv[3]);
    bfpair(a.z, qv[4], qv[5]);   bfpair(a.w, qv[6], qv[7]);
    bfpair(bq.x, qv[8], qv[9]);  bfpair(bq.y, qv[10], qv[11]);
    bfpair(bq.z, qv[12], qv[13]); bfpair(bq.w, qv[14], qv[15]);
  }
  __syncthreads();

  float s[33];
#pragma unroll
  for (int j = 0; j < 33; j++) {
    const int row = qi + j;                  // key row in slab
    uint4 a = *(const uint4*)&Ks[row][d0];
    uint4 c = *(const uint4*)&Ks[row][d0 + 8];
    float k0, k1;
    float a0 = 0.f, a1 = 0.f;
    bfpair(a.x, k0, k1); a0 += qv[0] * k0;  a1 += qv[1] * k1;
    bfpair(a.y, k0, k1); a0 += qv[2] * k0;  a1 += qv[3] * k1;
    bfpair(a.z, k0, k1); a0 += qv[4] * k0;  a1 += qv[5] * k1;
    bfpair(a.w, k0, k1); a0 += qv[6] * k0;  a1 += qv[7] * k1;
    bfpair(c.x, k0, k1); a0 += qv[8] * k0;  a1 += qv[9] * k1;
    bfpair(c.y, k0, k1); a0 += qv[10] * k0; a1 += qv[11] * k1;
    bfpair(c.z, k0, k1); a0 += qv[12] * k0; a1 += qv[13] * k1;
    bfpair(c.w, k0, k1); a0 += qv[14] * k0; a1 += qv[15] * k1;
    float sc = a0 + a1;
    sc += __shfl_xor(sc, 1);
    sc += __shfl_xor(sc, 2);
    int kidx = t - 16 + j;
    s[j] = (kidx >= 0 && kidx < T_LEN) ? sc * 0.125f : -INFINITY;
  }

  float m = s[0];
#pragma unroll
  for (int j = 1; j < 33; j++) m = fmaxf(m, s[j]);
  float l = 0.f;
#pragma unroll
  for (int j = 0; j < 33; j++) {
    float pp = __expf(s[j] - m);
    s[j] = pp;
    l += pp;
  }
  float inv = 1.0f / l;

  float o[16] = {};
#pragma unroll
  for (int j = 0; j < 33; j++) {
    const int row = qi + j;
    float pp = s[j];
    uint4 a = *(const uint4*)&Vs[row][d0];
    uint4 c = *(const uint4*)&Vs[row][d0 + 8];
    float v0, v1;
    bfpair(a.x, v0, v1); o[0]  += pp * v0; o[1]  += pp * v1;
    bfpair(a.y, v0, v1); o[2]  += pp * v0; o[3]  += pp * v1;
    bfpair(a.z, v0, v1); o[4]  += pp * v0; o[5]  += pp * v1;
    bfpair(a.w, v0, v1); o[6]  += pp * v0; o[7]  += pp * v1;
    bfpair(c.x, v0, v1); o[8]  += pp * v0; o[9]  += pp * v1;
    bfpair(c.y, v0, v1); o[10] += pp * v0; o[11] += pp * v1;
    bfpair(c.z, v0, v1); o[12] += pp * v0; o[13] += pp * v1;
    bfpair(c.w, v0, v1); o[14] += pp * v0; o[15] += pp * v1;
  }

  u16* orow = attn + ((size_t)(b * T_LEN + t)) * DMODEL + h * HD + d0;
  u16x8 ov;
#pragma unroll
  for (int z = 0; z < 8; z++) ov[z] = f2bf(o[z] * inv);
  *(u16x8*)orow = ov;
#pragma unroll
  for (int z = 0; z < 8; z++) ov[z] = f2bf(o[8 + z] * inv);
  *(u16x8*)(orow + 8) = ov;
}

// ---------------- launch ----------------
extern "C" void kernel_launch(void* const* d_in, const int* in_sizes, int n_in,
                              void* d_out, int out_size, void* d_ws, size_t ws_size,
                              hipStream_t stream) {
  const float* x  = (const float*)d_in[0];
  const float* Wq = (const float*)d_in[1];
  const float* bq = (const float*)d_in[2];
  const float* Wk = (const float*)d_in[3];
  const float* bk = (const float*)d_in[4];
  const float* Wv = (const float*)d_in[5];
  const float* bv = (const float*)d_in[6];
  const float* Wo = (const float*)d_in[7];
  const float* bo = (const float*)d_in[8];
  float* out = (float*)d_out;
  char* ws = (char*)d_ws;

  u16* xb   = (u16*)(ws);                 // 8192*768 bf16
  u16* wqkv = (u16*)(ws + 12582912);      // 2304*768 bf16
  u16* wo_b = (u16*)(ws + 16121856);      // 768*768 bf16
  u16* qkv  = (u16*)(ws + 17301504);      // 3*6291456 bf16
  u16* attn = (u16*)(ws + 55050240);      // 8192*768 bf16

  cvt_f32_bf16<<<6144, 256, 0, stream>>>(x, xb, 6291456);
  cvt_w4<<<dim3(576, 4), 256, 0, stream>>>(Wq, Wk, Wv, Wo,
                                           wqkv, wqkv + 589824, wqkv + 1179648, wo_b);

  gemm_bt<0><<<dim3(64, 18), 256, 0, stream>>>(xb, wqkv, bq, bk, bv, (void*)qkv);
  attn_local<<<dim3(64, 12, 2), 256, 0, stream>>>(qkv, attn);
  gemm_bt<1><<<dim3(64, 6), 256, 0, stream>>>(attn, wo_b, bo, bo, bo, (void*)out);
}

// Round 4
// 187.554 us; speedup vs baseline: 1.1726x; 1.0087x over previous
//
#include <hip/hip_runtime.h>
#include <math.h>
#include <cstdint>
#include <cstddef>

typedef unsigned short u16;
typedef short bf16x8 __attribute__((ext_vector_type(8)));
typedef float f32x4 __attribute__((ext_vector_type(4)));
typedef u16 u16x8 __attribute__((ext_vector_type(8)));
typedef u16 u16x4 __attribute__((ext_vector_type(4)));

#define T_LEN 4096
#define NH 12
#define HD 64
#define DMODEL 768
#define GK 768                    // K dim for both GEMMs
#define QKV_STRIDE 6291456ul      // elems per q/k/v tensor = 8192*768

__device__ __forceinline__ u16 f2bf(float x) {
  union { float f; unsigned u; } v; v.f = x;
  unsigned r = v.u + 0x7fffu + ((v.u >> 16) & 1u);
  return (u16)(r >> 16);
}
__device__ __forceinline__ float bf2f(u16 x) {
  union { unsigned u; float f; } v; v.u = ((unsigned)x) << 16;
  return v.f;
}
__device__ __forceinline__ void bfpair(unsigned u, float& lo, float& hi) {
  union { unsigned u; float f; } a, b;
  a.u = u << 16; b.u = u & 0xffff0000u;
  lo = a.f; hi = b.f;
}

__device__ __forceinline__ void async16(const u16* g, u16* l) {
  __builtin_amdgcn_global_load_lds(
      (const __attribute__((address_space(1))) unsigned int*)g,
      (__attribute__((address_space(3))) unsigned int*)l, 16, 0, 0);
}

// ---------------- fp32 -> bf16 conversion ----------------
__global__ void cvt_f32_bf16(const float* __restrict__ s, u16* __restrict__ d, int n) {
  int i = (blockIdx.x * blockDim.x + threadIdx.x) * 4;
  if (i >= n) return;
  float4 v = *(const float4*)(s + i);
  u16x4 o;
  o[0] = f2bf(v.x); o[1] = f2bf(v.y); o[2] = f2bf(v.z); o[3] = f2bf(v.w);
  *(u16x4*)(d + i) = o;
}

__global__ void cvt_w4(const float* __restrict__ s0, const float* __restrict__ s1,
                       const float* __restrict__ s2, const float* __restrict__ s3,
                       u16* __restrict__ d0, u16* __restrict__ d1,
                       u16* __restrict__ d2, u16* __restrict__ d3) {
  const float* s; u16* d;
  switch (blockIdx.y) {
    case 0: s = s0; d = d0; break;
    case 1: s = s1; d = d1; break;
    case 2: s = s2; d = d2; break;
    default: s = s3; d = d3; break;
  }
  int i = (blockIdx.x * blockDim.x + threadIdx.x) * 4;
  float4 v = *(const float4*)(s + i);
  u16x4 o;
  o[0] = f2bf(v.x); o[1] = f2bf(v.y); o[2] = f2bf(v.z); o[3] = f2bf(v.w);
  *(u16x4*)(d + i) = o;
}

// ---------------- GEMM: C = A[M,K] * B[N,K]^T + bias ----------------
// 128x128 tile, BK=32, 256 threads (4 waves 2x2 of 64x64), 16x16x32 bf16 MFMA.
// XOR chunk swizzle on LDS tiles: LDS[row][c'] holds global chunk c'^((row>>1)&3)
// -> fragment b128 reads are 2-way (free) instead of 8-way.
// EPI=0: bf16 out, 3 tensors [8192,768] each, via 32KB LDS C-tile (coalesced b128 stores)
// EPI=1: fp32 out [8192,768], direct stores.
#define BM 128
#define BN 128
#define BK 32

template <int EPI>
__global__ __launch_bounds__(256)
void gemm_bt(const u16* __restrict__ A, const u16* __restrict__ B,
             const float* __restrict__ bias0, const float* __restrict__ bias1,
             const float* __restrict__ bias2, void* __restrict__ outp) {
  extern __shared__ __align__(16) u16 smem[];
  u16* As = smem;                 // BM*BK = 4096 u16 (8KB)
  u16* Bs = smem + BM * BK;       // BN*BK (8KB)
  u16* Cs = smem + (BM + BN) * BK; // EPI=0 only: BM*BN (32KB)

  const int tid  = threadIdx.x;
  const int lane = tid & 63;
  const int wave = tid >> 6;
  const int wm = wave & 1, wn = wave >> 1;
  const long am0 = (long)blockIdx.x * BM;
  const long bn0 = (long)blockIdx.y * BN;
  const int r16 = lane & 15;
  const int kh  = lane >> 4;
  const int sw8 = (kh ^ ((r16 >> 1) & 3)) * 8;   // swizzled chunk offset for frag reads

  f32x4 acc[4][4] = {};

  // staging: lane l -> row l>>2, global chunk (l&3)^((l>>3)&3); LDS dest lane-linear
  const int srow   = lane >> 2;
  const int schunk = ((lane & 3) ^ ((lane >> 3) & 3)) * 8;
  const u16* Ag = A + (am0 + wave * 16 + srow) * GK + schunk;
  const u16* Bg = B + (bn0 + wave * 16 + srow) * GK + schunk;
  u16* Al0 = &As[(wave * 16) * BK];
  u16* Al1 = &As[(64 + wave * 16) * BK];
  u16* Bl0 = &Bs[(wave * 16) * BK];
  u16* Bl1 = &Bs[(64 + wave * 16) * BK];

  for (int kt = 0; kt < GK; kt += BK) {
    __syncthreads();
    async16(Ag + kt, Al0);
    async16(Ag + 64 * GK + kt, Al1);
    async16(Bg + kt, Bl0);
    async16(Bg + 64 * GK + kt, Bl1);
    __syncthreads();
    bf16x8 af[4], bfr[4];
#pragma unroll
    for (int i = 0; i < 4; i++)
      af[i] = *(const bf16x8*)&As[(wm * 64 + i * 16 + r16) * BK + sw8];
#pragma unroll
    for (int j = 0; j < 4; j++)
      bfr[j] = *(const bf16x8*)&Bs[(wn * 64 + j * 16 + r16) * BK + sw8];
#pragma unroll
    for (int i = 0; i < 4; i++)
#pragma unroll
      for (int j = 0; j < 4; j++)
        acc[i][j] = __builtin_amdgcn_mfma_f32_16x16x32_bf16(af[i], bfr[j], acc[i][j], 0, 0, 0);
  }

  const int m0 = (int)am0 + wm * 64;   // global row base of this wave's subtile
  const int n0w = wn * 64;             // local col base of this wave's subtile

  if (EPI == 0) {
    // tile fully within one of q/k/v (768 = 6 tiles of 128)
    const int tens = (int)(bn0 >= 1536 ? 2 : (bn0 >= 768 ? 1 : 0));
    const int c0 = (int)bn0 - tens * 768;
    const float* bp = (tens == 0) ? bias0 : ((tens == 1) ? bias1 : bias2);
    u16* outb = (u16*)outp + (size_t)tens * QKV_STRIDE;

    // 1) acc -> Cs (bf16) with bias
#pragma unroll
    for (int j = 0; j < 4; j++) {
      float bv = bp[c0 + n0w + j * 16 + r16];
      int lc = n0w + j * 16 + r16;
#pragma unroll
      for (int i = 0; i < 4; i++) {
        int lr = wm * 64 + i * 16 + kh * 4;
#pragma unroll
        for (int r = 0; r < 4; r++)
          Cs[(lr + r) * BN + lc] = f2bf(acc[i][j][r] + bv);
      }
    }
    __syncthreads();
    // 2) cooperative coalesced store: 2048 16B-chunks (16 chunks/row x 128 rows)
#pragma unroll
    for (int z = 0; z < 8; z++) {
      int cidx = z * 256 + tid;
      int row = cidx >> 4, ch = (cidx & 15) * 8;
      uint4 val = *(const uint4*)&Cs[row * BN + ch];
      *(uint4*)(outb + (size_t)(am0 + row) * DMODEL + c0 + ch) = val;
    }
  } else {
    float* O = (float*)outp;
#pragma unroll
    for (int i = 0; i < 4; i++) {
#pragma unroll
      for (int r = 0; r < 4; r++) {
        int row = m0 + i * 16 + kh * 4 + r;
        float* orow = O + (size_t)row * DMODEL;
#pragma unroll
        for (int j = 0; j < 4; j++) {
          int col = (int)bn0 + n0w + j * 16 + r16;
          orow[col] = acc[i][j][r] + bias0[col];
        }
      }
    }
  }
}

// ---------------- banded local attention ----------------
// qkv layout [3][8192][768]; row = b*T+t, col = h*64+d.
// 64 queries/block, 256 threads: 4 threads/query x 16 dims.
#define QB 64
#define SLAB 96
#define KSTR 72

__global__ __launch_bounds__(256)
void attn_local(const u16* __restrict__ qkv, u16* __restrict__ attn) {
  __shared__ __align__(16) u16 Ks[SLAB][KSTR];
  __shared__ __align__(16) u16 Vs[SLAB][KSTR];
  const int tid = threadIdx.x;
  const int q0 = blockIdx.x * QB;
  const int h = blockIdx.y, b = blockIdx.z;
  const size_t rowbase = (size_t)b * T_LEN;
  const int hc = h * HD;
  const u16* Qg = qkv;
  const u16* Kg = qkv + QKV_STRIDE;
  const u16* Vg = qkv + 2 * QKV_STRIDE;

  for (int e = tid; e < SLAB * 8; e += 256) {
    int r = e >> 3, c8 = (e & 7) * 8;
    int g = q0 - 16 + r;
    if (g >= 0 && g < T_LEN) {
      size_t off = (rowbase + g) * DMODEL + hc + c8;
      *(u16x8*)&Ks[r][c8] = *(const u16x8*)(Kg + off);
      *(u16x8*)&Vs[r][c8] = *(const u16x8*)(Vg + off);
    } else {
      u16x8 zz = {0, 0, 0, 0, 0, 0, 0, 0};
      *(u16x8*)&Ks[r][c8] = zz;
      *(u16x8*)&Vs[r][c8] = zz;
    }
  }

  const int qi = tid >> 2;
  const int p  = tid & 3;
  const int d0 = p * 16;
  const int t  = q0 + qi;

  float qv[16];
  {
    const u16* qrow = Qg + (rowbase + t) * DMODEL + hc + d0;
    uint4 a = *(const uint4*)qrow;
    uint4 bq = *(const uint4*)(qrow + 8);
    bfpair(a.x, qv[0], qv[1]);   bfpair(a.y, qv[2], qv[3]);
    bfpair(a.z, qv[4], qv[5]);   bfpair(a.w, qv[6], qv[7]);
    bfpair(bq.x, qv[8], qv[9]);  bfpair(bq.y, qv[10], qv[11]);
    bfpair(bq.z, qv[12], qv[13]); bfpair(bq.w, qv[14], qv[15]);
  }
  __syncthreads();

  float s[33];
#pragma unroll
  for (int j = 0; j < 33; j++) {
    const int row = qi + j;
    uint4 a = *(const uint4*)&Ks[row][d0];
    uint4 c = *(const uint4*)&Ks[row][d0 + 8];
    float k0, k1;
    float a0 = 0.f, a1 = 0.f;
    bfpair(a.x, k0, k1); a0 += qv[0] * k0;  a1 += qv[1] * k1;
    bfpair(a.y, k0, k1); a0 += qv[2] * k0;  a1 += qv[3] * k1;
    bfpair(a.z, k0, k1); a0 += qv[4] * k0;  a1 += qv[5] * k1;
    bfpair(a.w, k0, k1); a0 += qv[6] * k0;  a1 += qv[7] * k1;
    bfpair(c.x, k0, k1); a0 += qv[8] * k0;  a1 += qv[9] * k1;
    bfpair(c.y, k0, k1); a0 += qv[10] * k0; a1 += qv[11] * k1;
    bfpair(c.z, k0, k1); a0 += qv[12] * k0; a1 += qv[13] * k1;
    bfpair(c.w, k0, k1); a0 += qv[14] * k0; a1 += qv[15] * k1;
    float sc = a0 + a1;
    sc += __shfl_xor(sc, 1);
    sc += __shfl_xor(sc, 2);
    int kidx = t - 16 + j;
    s[j] = (kidx >= 0 && kidx < T_LEN) ? sc * 0.125f : -INFINITY;
  }

  float m = s[0];
#pragma unroll
  for (int j = 1; j < 33; j++) m = fmaxf(m, s[j]);
  float l = 0.f;
#pragma unroll
  for (int j = 0; j < 33; j++) {
    float pp = __expf(s[j] - m);
    s[j] = pp;
    l += pp;
  }
  float inv = 1.0f / l;

  float o[16] = {};
#pragma unroll
  for (int j = 0; j < 33; j++) {
    const int row = qi + j;
    float pp = s[j];
    uint4 a = *(const uint4*)&Vs[row][d0];
    uint4 c = *(const uint4*)&Vs[row][d0 + 8];
    float v0, v1;
    bfpair(a.x, v0, v1); o[0]  += pp * v0; o[1]  += pp * v1;
    bfpair(a.y, v0, v1); o[2]  += pp * v0; o[3]  += pp * v1;
    bfpair(a.z, v0, v1); o[4]  += pp * v0; o[5]  += pp * v1;
    bfpair(a.w, v0, v1); o[6]  += pp * v0; o[7]  += pp * v1;
    bfpair(c.x, v0, v1); o[8]  += pp * v0; o[9]  += pp * v1;
    bfpair(c.y, v0, v1); o[10] += pp * v0; o[11] += pp * v1;
    bfpair(c.z, v0, v1); o[12] += pp * v0; o[13] += pp * v1;
    bfpair(c.w, v0, v1); o[14] += pp * v0; o[15] += pp * v1;
  }

  u16* orow = attn + (rowbase + t) * DMODEL + hc + d0;
  u16x8 ov;
#pragma unroll
  for (int z = 0; z < 8; z++) ov[z] = f2bf(o[z] * inv);
  *(u16x8*)orow = ov;
#pragma unroll
  for (int z = 0; z < 8; z++) ov[z] = f2bf(o[8 + z] * inv);
  *(u16x8*)(orow + 8) = ov;
}

// ---------------- launch ----------------
extern "C" void kernel_launch(void* const* d_in, const int* in_sizes, int n_in,
                              void* d_out, int out_size, void* d_ws, size_t ws_size,
                              hipStream_t stream) {
  const float* x  = (const float*)d_in[0];
  const float* Wq = (const float*)d_in[1];
  const float* bq = (const float*)d_in[2];
  const float* Wk = (const float*)d_in[3];
  const float* bk = (const float*)d_in[4];
  const float* Wv = (const float*)d_in[5];
  const float* bv = (const float*)d_in[6];
  const float* Wo = (const float*)d_in[7];
  const float* bo = (const float*)d_in[8];
  float* out = (float*)d_out;
  char* ws = (char*)d_ws;

  u16* xb   = (u16*)(ws);                 // 8192*768 bf16
  u16* wqkv = (u16*)(ws + 12582912);      // 2304*768 bf16
  u16* wo_b = (u16*)(ws + 16121856);      // 768*768 bf16
  u16* qkv  = (u16*)(ws + 17301504);      // 3*6291456 bf16
  u16* attn = (u16*)(ws + 55050240);      // 8192*768 bf16

  cvt_f32_bf16<<<6144, 256, 0, stream>>>(x, xb, 6291456);
  cvt_w4<<<dim3(576, 4), 256, 0, stream>>>(Wq, Wk, Wv, Wo,
                                           wqkv, wqkv + 589824, wqkv + 1179648, wo_b);

  gemm_bt<0><<<dim3(64, 18), 256, 49152, stream>>>(xb, wqkv, bq, bk, bv, (void*)qkv);
  attn_local<<<dim3(64, 12, 2), 256, 0, stream>>>(qkv, attn);
  gemm_bt<1><<<dim3(64, 6), 256, 16384, stream>>>(attn, wo_b, bo, bo, bo, (void*)out);
}

// Round 5
// 187.317 us; speedup vs baseline: 1.1741x; 1.0013x over previous
//
#include <hip/hip_runtime.h>
#include <math.h>
#include <cstdint>
#include <cstddef>

typedef unsigned short u16;
typedef short bf16x8 __attribute__((ext_vector_type(8)));
typedef float f32x4 __attribute__((ext_vector_type(4)));
typedef u16 u16x8 __attribute__((ext_vector_type(8)));
typedef u16 u16x4 __attribute__((ext_vector_type(4)));

#define T_LEN 4096
#define NH 12
#define HD 64
#define DMODEL 768
#define GK 768                    // K dim for both GEMMs
#define QKV_STRIDE 6291456ul      // elems per q/k/v tensor = 8192*768

__device__ __forceinline__ u16 f2bf(float x) {
  union { float f; unsigned u; } v; v.f = x;
  unsigned r = v.u + 0x7fffu + ((v.u >> 16) & 1u);
  return (u16)(r >> 16);
}
__device__ __forceinline__ float bf2f(u16 x) {
  union { unsigned u; float f; } v; v.u = ((unsigned)x) << 16;
  return v.f;
}
__device__ __forceinline__ void bfpair(unsigned u, float& lo, float& hi) {
  union { unsigned u; float f; } a, b;
  a.u = u << 16; b.u = u & 0xffff0000u;
  lo = a.f; hi = b.f;
}

__device__ __forceinline__ void async16(const u16* g, u16* l) {
  __builtin_amdgcn_global_load_lds(
      (const __attribute__((address_space(1))) unsigned int*)g,
      (__attribute__((address_space(3))) unsigned int*)l, 16, 0, 0);
}

// ---------------- fused fp32 -> bf16 conversion (x + 4 weights, one launch) ----------------
__global__ void cvt_all(const float* __restrict__ x,
                        const float* __restrict__ Wq, const float* __restrict__ Wk,
                        const float* __restrict__ Wv, const float* __restrict__ Wo,
                        u16* __restrict__ xb, u16* __restrict__ wqkv, u16* __restrict__ wo_b) {
  int bx = blockIdx.x;
  const float* s; u16* d; int base;
  if (bx < 6144)      { s = x;  d = xb;             base = bx; }
  else if (bx < 6720) { s = Wq; d = wqkv;           base = bx - 6144; }
  else if (bx < 7296) { s = Wk; d = wqkv + 589824;  base = bx - 6720; }
  else if (bx < 7872) { s = Wv; d = wqkv + 1179648; base = bx - 7296; }
  else                { s = Wo; d = wo_b;           base = bx - 7872; }
  int i = (base * 256 + (int)threadIdx.x) * 4;
  float4 v = *(const float4*)(s + i);
  u16x4 o;
  o[0] = f2bf(v.x); o[1] = f2bf(v.y); o[2] = f2bf(v.z); o[3] = f2bf(v.w);
  *(u16x4*)(d + i) = o;
}

// ---------------- GEMM: C = A[M,K] * B[N,K]^T + bias ----------------
// Tile BMt x 128 (BMt = MI*32), BK=32, 256 threads (4 waves 2x2), 16x16x32 bf16 MFMA.
// XOR chunk swizzle on LDS tiles: LDS[row][c'] holds global chunk c'^((row>>1)&3)
// -> fragment b128 reads conflict-free. No C-staging LDS (keeps occupancy high).
// EPI=0: bf16 direct scatter into 3 tensors [8192,768] each (+bias per tensor)
// EPI=1: fp32 direct store [8192,768] (+bias0)
#define BN 128
#define BK 32

template <int EPI, int MI>
__global__ __launch_bounds__(256)
void gemm_bt(const u16* __restrict__ A, const u16* __restrict__ B,
             const float* __restrict__ bias0, const float* __restrict__ bias1,
             const float* __restrict__ bias2, void* __restrict__ outp) {
  constexpr int BMt = MI * 32;
  __shared__ __align__(16) u16 As[BMt * BK];
  __shared__ __align__(16) u16 Bs[BN * BK];

  const int tid  = threadIdx.x;
  const int lane = tid & 63;
  const int wave = tid >> 6;
  const int wm = wave & 1, wn = wave >> 1;
  const long am0 = (long)blockIdx.x * BMt;
  const long bn0 = (long)blockIdx.y * BN;
  const int r16 = lane & 15;
  const int kh  = lane >> 4;
  const int sw8 = (kh ^ ((r16 >> 1) & 3)) * 8;   // swizzled chunk offset for frag reads

  f32x4 acc[MI][4] = {};

  // staging: lane l -> row l>>2, global chunk (l&3)^((l>>3)&3); LDS dest lane-linear
  const int srow   = lane >> 2;
  const int schunk = ((lane & 3) ^ ((lane >> 3) & 3)) * 8;
  const u16* Ag = A + (am0 + wave * 16 + srow) * GK + schunk;
  const u16* Bg = B + (bn0 + wave * 16 + srow) * GK + schunk;
  u16* Bl0 = &Bs[(wave * 16) * BK];
  u16* Bl1 = &Bs[(64 + wave * 16) * BK];

  for (int kt = 0; kt < GK; kt += BK) {
    __syncthreads();
#pragma unroll
    for (int s = 0; s < MI / 2; s++)
      async16(Ag + (size_t)(s * 64) * GK + kt, &As[(s * 64 + wave * 16) * BK]);
    async16(Bg + kt, Bl0);
    async16(Bg + 64 * GK + kt, Bl1);
    __syncthreads();
    bf16x8 af[MI], bfr[4];
#pragma unroll
    for (int i = 0; i < MI; i++)
      af[i] = *(const bf16x8*)&As[(wm * MI * 16 + i * 16 + r16) * BK + sw8];
#pragma unroll
    for (int j = 0; j < 4; j++)
      bfr[j] = *(const bf16x8*)&Bs[(wn * 64 + j * 16 + r16) * BK + sw8];
#pragma unroll
    for (int i = 0; i < MI; i++)
#pragma unroll
      for (int j = 0; j < 4; j++)
        acc[i][j] = __builtin_amdgcn_mfma_f32_16x16x32_bf16(af[i], bfr[j], acc[i][j], 0, 0, 0);
  }

  const int m0 = (int)am0 + wm * MI * 16;   // global row base of this wave's subtile

  if (EPI == 0) {
    // tile fully within one of q/k/v (768 is a multiple of 128)
    const int tens = (int)(bn0 / 768);
    const int c0 = (int)bn0 - tens * 768;
    const float* bp = (tens == 0) ? bias0 : ((tens == 1) ? bias1 : bias2);
    u16* outb = (u16*)outp + (size_t)tens * QKV_STRIDE;
#pragma unroll
    for (int j = 0; j < 4; j++) {
      int col = c0 + wn * 64 + j * 16 + r16;
      float bv = bp[col];
#pragma unroll
      for (int i = 0; i < MI; i++) {
#pragma unroll
        for (int r = 0; r < 4; r++) {
          int row = m0 + i * 16 + kh * 4 + r;
          outb[(size_t)row * DMODEL + col] = f2bf(acc[i][j][r] + bv);
        }
      }
    }
  } else {
    float* O = (float*)outp;
#pragma unroll
    for (int i = 0; i < MI; i++) {
#pragma unroll
      for (int r = 0; r < 4; r++) {
        int row = m0 + i * 16 + kh * 4 + r;
        float* orow = O + (size_t)row * DMODEL;
#pragma unroll
        for (int j = 0; j < 4; j++) {
          int col = (int)bn0 + wn * 64 + j * 16 + r16;
          orow[col] = acc[i][j][r] + bias0[col];
        }
      }
    }
  }
}

// ---------------- banded local attention ----------------
// qkv layout [3][8192][768]; row = b*T+t, col = h*64+d.
// 64 queries/block, 256 threads: 4 threads/query x 16 dims.
#define QB 64
#define SLAB 96
#define KSTR 72

__global__ __launch_bounds__(256)
void attn_local(const u16* __restrict__ qkv, u16* __restrict__ attn) {
  __shared__ __align__(16) u16 Ks[SLAB][KSTR];
  __shared__ __align__(16) u16 Vs[SLAB][KSTR];
  const int tid = threadIdx.x;
  const int q0 = blockIdx.x * QB;
  const int h = blockIdx.y, b = blockIdx.z;
  const size_t rowbase = (size_t)b * T_LEN;
  const int hc = h * HD;
  const u16* Qg = qkv;
  const u16* Kg = qkv + QKV_STRIDE;
  const u16* Vg = qkv + 2 * QKV_STRIDE;

  for (int e = tid; e < SLAB * 8; e += 256) {
    int r = e >> 3, c8 = (e & 7) * 8;
    int g = q0 - 16 + r;
    if (g >= 0 && g < T_LEN) {
      size_t off = (rowbase + g) * DMODEL + hc + c8;
      *(u16x8*)&Ks[r][c8] = *(const u16x8*)(Kg + off);
      *(u16x8*)&Vs[r][c8] = *(const u16x8*)(Vg + off);
    } else {
      u16x8 zz = {0, 0, 0, 0, 0, 0, 0, 0};
      *(u16x8*)&Ks[r][c8] = zz;
      *(u16x8*)&Vs[r][c8] = zz;
    }
  }

  const int qi = tid >> 2;
  const int p  = tid & 3;
  const int d0 = p * 16;
  const int t  = q0 + qi;

  float qv[16];
  {
    const u16* qrow = Qg + (rowbase + t) * DMODEL + hc + d0;
    uint4 a = *(const uint4*)qrow;
    uint4 bq = *(const uint4*)(qrow + 8);
    bfpair(a.x, qv[0], qv[1]);   bfpair(a.y, qv[2], qv[3]);
    bfpair(a.z, qv[4], qv[5]);   bfpair(a.w, qv[6], qv[7]);
    bfpair(bq.x, qv[8], qv[9]);  bfpair(bq.y, qv[10], qv[11]);
    bfpair(bq.z, qv[12], qv[13]); bfpair(bq.w, qv[14], qv[15]);
  }
  __syncthreads();

  float s[33];
#pragma unroll
  for (int j = 0; j < 33; j++) {
    const int row = qi + j;
    uint4 a = *(const uint4*)&Ks[row][d0];
    uint4 c = *(const uint4*)&Ks[row][d0 + 8];
    float k0, k1;
    float a0 = 0.f, a1 = 0.f;
    bfpair(a.x, k0, k1); a0 += qv[0] * k0;  a1 += qv[1] * k1;
    bfpair(a.y, k0, k1); a0 += qv[2] * k0;  a1 += qv[3] * k1;
    bfpair(a.z, k0, k1); a0 += qv[4] * k0;  a1 += qv[5] * k1;
    bfpair(a.w, k0, k1); a0 += qv[6] * k0;  a1 += qv[7] * k1;
    bfpair(c.x, k0, k1); a0 += qv[8] * k0;  a1 += qv[9] * k1;
    bfpair(c.y, k0, k1); a0 += qv[10] * k0; a1 += qv[11] * k1;
    bfpair(c.z, k0, k1); a0 += qv[12] * k0; a1 += qv[13] * k1;
    bfpair(c.w, k0, k1); a0 += qv[14] * k0; a1 += qv[15] * k1;
    float sc = a0 + a1;
    sc += __shfl_xor(sc, 1);
    sc += __shfl_xor(sc, 2);
    int kidx = t - 16 + j;
    s[j] = (kidx >= 0 && kidx < T_LEN) ? sc * 0.125f : -INFINITY;
  }

  float m = s[0];
#pragma unroll
  for (int j = 1; j < 33; j++) m = fmaxf(m, s[j]);
  float l = 0.f;
#pragma unroll
  for (int j = 0; j < 33; j++) {
    float pp = __expf(s[j] - m);
    s[j] = pp;
    l += pp;
  }
  float inv = 1.0f / l;

  float o[16] = {};
#pragma unroll
  for (int j = 0; j < 33; j++) {
    const int row = qi + j;
    float pp = s[j];
    uint4 a = *(const uint4*)&Vs[row][d0];
    uint4 c = *(const uint4*)&Vs[row][d0 + 8];
    float v0, v1;
    bfpair(a.x, v0, v1); o[0]  += pp * v0; o[1]  += pp * v1;
    bfpair(a.y, v0, v1); o[2]  += pp * v0; o[3]  += pp * v1;
    bfpair(a.z, v0, v1); o[4]  += pp * v0; o[5]  += pp * v1;
    bfpair(a.w, v0, v1); o[6]  += pp * v0; o[7]  += pp * v1;
    bfpair(c.x, v0, v1); o[8]  += pp * v0; o[9]  += pp * v1;
    bfpair(c.y, v0, v1); o[10] += pp * v0; o[11] += pp * v1;
    bfpair(c.z, v0, v1); o[12] += pp * v0; o[13] += pp * v1;
    bfpair(c.w, v0, v1); o[14] += pp * v0; o[15] += pp * v1;
  }

  u16* orow = attn + (rowbase + t) * DMODEL + hc + d0;
  u16x8 ov;
#pragma unroll
  for (int z = 0; z < 8; z++) ov[z] = f2bf(o[z] * inv);
  *(u16x8*)orow = ov;
#pragma unroll
  for (int z = 0; z < 8; z++) ov[z] = f2bf(o[8 + z] * inv);
  *(u16x8*)(orow + 8) = ov;
}

// ---------------- launch ----------------
extern "C" void kernel_launch(void* const* d_in, const int* in_sizes, int n_in,
                              void* d_out, int out_size, void* d_ws, size_t ws_size,
                              hipStream_t stream) {
  const float* x  = (const float*)d_in[0];
  const float* Wq = (const float*)d_in[1];
  const float* bq = (const float*)d_in[2];
  const float* Wk = (const float*)d_in[3];
  const float* bk = (const float*)d_in[4];
  const float* Wv = (const float*)d_in[5];
  const float* bv = (const float*)d_in[6];
  const float* Wo = (const float*)d_in[7];
  const float* bo = (const float*)d_in[8];
  float* out = (float*)d_out;
  char* ws = (char*)d_ws;

  u16* xb   = (u16*)(ws);                 // 8192*768 bf16
  u16* wqkv = (u16*)(ws + 12582912);      // 2304*768 bf16
  u16* wo_b = (u16*)(ws + 16121856);      // 768*768 bf16
  u16* qkv  = (u16*)(ws + 17301504);      // 3*6291456 bf16
  u16* attn = (u16*)(ws + 55050240);      // 8192*768 bf16

  cvt_all<<<8448, 256, 0, stream>>>(x, Wq, Wk, Wv, Wo, xb, wqkv, wo_b);

  gemm_bt<0, 4><<<dim3(64, 18), 256, 0, stream>>>(xb, wqkv, bq, bk, bv, (void*)qkv);
  attn_local<<<dim3(64, 12, 2), 256, 0, stream>>>(qkv, attn);
  gemm_bt<1, 2><<<dim3(128, 6), 256, 0, stream>>>(attn, wo_b, bo, bo, bo, (void*)out);
}

// Round 6
// 177.385 us; speedup vs baseline: 1.2399x; 1.0560x over previous
//
#include <hip/hip_runtime.h>
#include <math.h>
#include <cstdint>
#include <cstddef>

typedef unsigned short u16;
typedef short bf16x8 __attribute__((ext_vector_type(8)));
typedef float f32x4 __attribute__((ext_vector_type(4)));
typedef u16 u16x8 __attribute__((ext_vector_type(8)));
typedef u16 u16x4 __attribute__((ext_vector_type(4)));

#define T_LEN 4096
#define NH 12
#define HD 64
#define DMODEL 768
#define GK 768                    // K dim for both GEMMs
#define QKV_STRIDE 6291456ul      // elems per q/k/v tensor = 8192*768

__device__ __forceinline__ u16 f2bf(float x) {
  union { float f; unsigned u; } v; v.f = x;
  unsigned r = v.u + 0x7fffu + ((v.u >> 16) & 1u);
  return (u16)(r >> 16);
}

__device__ __forceinline__ void async16(const u16* g, u16* l) {
  __builtin_amdgcn_global_load_lds(
      (const __attribute__((address_space(1))) unsigned int*)g,
      (__attribute__((address_space(3))) unsigned int*)l, 16, 0, 0);
}

// ---------------- fused fp32 -> bf16 conversion (x + 4 weights, one launch) ----------------
__global__ void cvt_all(const float* __restrict__ x,
                        const float* __restrict__ Wq, const float* __restrict__ Wk,
                        const float* __restrict__ Wv, const float* __restrict__ Wo,
                        u16* __restrict__ xb, u16* __restrict__ wqkv, u16* __restrict__ wo_b) {
  int bx = blockIdx.x;
  const float* s; u16* d; int base;
  if (bx < 6144)      { s = x;  d = xb;             base = bx; }
  else if (bx < 6720) { s = Wq; d = wqkv;           base = bx - 6144; }
  else if (bx < 7296) { s = Wk; d = wqkv + 589824;  base = bx - 6720; }
  else if (bx < 7872) { s = Wv; d = wqkv + 1179648; base = bx - 7296; }
  else                { s = Wo; d = wo_b;           base = bx - 7872; }
  int i = (base * 256 + (int)threadIdx.x) * 4;
  float4 v = *(const float4*)(s + i);
  u16x4 o;
  o[0] = f2bf(v.x); o[1] = f2bf(v.y); o[2] = f2bf(v.z); o[3] = f2bf(v.w);
  *(u16x4*)(d + i) = o;
}

// ---------------- GEMM: C = A[M,K] * B[N,K]^T + bias ----------------
// Tile BMt x 128 (BMt = MI*32), BK=32, 256 threads (4 waves 2x2), 16x16x32 bf16 MFMA.
// XOR chunk swizzle on LDS tiles (conflict-free frag reads).
// EPI=0: bf16 out. Q,K tensors row-major [8192,768]; V tensor written
//        block-transposed: V[b*12+h][t/16][d(64)][t%16] (for MFMA attention B-frags).
// EPI=1: fp32 direct store [8192,768] (+bias0)
#define BN 128
#define BK 32

template <int EPI, int MI>
__global__ __launch_bounds__(256)
void gemm_bt(const u16* __restrict__ A, const u16* __restrict__ B,
             const float* __restrict__ bias0, const float* __restrict__ bias1,
             const float* __restrict__ bias2, void* __restrict__ outp) {
  constexpr int BMt = MI * 32;
  __shared__ __align__(16) u16 As[BMt * BK];
  __shared__ __align__(16) u16 Bs[BN * BK];

  const int tid  = threadIdx.x;
  const int lane = tid & 63;
  const int wave = tid >> 6;
  const int wm = wave & 1, wn = wave >> 1;
  const long am0 = (long)blockIdx.x * BMt;
  const long bn0 = (long)blockIdx.y * BN;
  const int r16 = lane & 15;
  const int kh  = lane >> 4;
  const int sw8 = (kh ^ ((r16 >> 1) & 3)) * 8;   // swizzled chunk offset for frag reads

  f32x4 acc[MI][4] = {};

  // staging: lane l -> row l>>2, global chunk (l&3)^((l>>3)&3); LDS dest lane-linear
  const int srow   = lane >> 2;
  const int schunk = ((lane & 3) ^ ((lane >> 3) & 3)) * 8;
  const u16* Ag = A + (am0 + wave * 16 + srow) * GK + schunk;
  const u16* Bg = B + (bn0 + wave * 16 + srow) * GK + schunk;
  u16* Bl0 = &Bs[(wave * 16) * BK];
  u16* Bl1 = &Bs[(64 + wave * 16) * BK];

  for (int kt = 0; kt < GK; kt += BK) {
    __syncthreads();
#pragma unroll
    for (int s = 0; s < MI / 2; s++)
      async16(Ag + (size_t)(s * 64) * GK + kt, &As[(s * 64 + wave * 16) * BK]);
    async16(Bg + kt, Bl0);
    async16(Bg + 64 * GK + kt, Bl1);
    __syncthreads();
    bf16x8 af[MI], bfr[4];
#pragma unroll
    for (int i = 0; i < MI; i++)
      af[i] = *(const bf16x8*)&As[(wm * MI * 16 + i * 16 + r16) * BK + sw8];
#pragma unroll
    for (int j = 0; j < 4; j++)
      bfr[j] = *(const bf16x8*)&Bs[(wn * 64 + j * 16 + r16) * BK + sw8];
#pragma unroll
    for (int i = 0; i < MI; i++)
#pragma unroll
      for (int j = 0; j < 4; j++)
        acc[i][j] = __builtin_amdgcn_mfma_f32_16x16x32_bf16(af[i], bfr[j], acc[i][j], 0, 0, 0);
  }

  const int m0 = (int)am0 + wm * MI * 16;   // global row base of this wave's subtile

  if (EPI == 0) {
    const int tens = (int)(bn0 / 768);
    const int c0 = (int)bn0 - tens * 768;
    const float* bp = (tens == 0) ? bias0 : ((tens == 1) ? bias1 : bias2);
    if (tens < 2) {
      // Q or K: row-major [8192][768]
      u16* outb = (u16*)outp + (size_t)tens * QKV_STRIDE;
#pragma unroll
      for (int j = 0; j < 4; j++) {
        int col = c0 + wn * 64 + j * 16 + r16;
        float bv = bp[col];
#pragma unroll
        for (int i = 0; i < MI; i++) {
#pragma unroll
          for (int r = 0; r < 4; r++) {
            int row = m0 + i * 16 + kh * 4 + r;
            outb[(size_t)row * DMODEL + col] = f2bf(acc[i][j][r] + bv);
          }
        }
      }
    } else {
      // V: block-transposed [b*12+h][t>>4][d][t&15]
      u16* vtb = (u16*)outp + 2 * QKV_STRIDE;
#pragma unroll
      for (int j = 0; j < 4; j++) {
        int cl = c0 + wn * 64 + j * 16;      // uniform over lanes (mult of 16)
        int hj = cl >> 6, dbase = cl & 63;
        float bv = bp[cl + r16];
#pragma unroll
        for (int i = 0; i < MI; i++) {
#pragma unroll
          for (int r = 0; r < 4; r++) {
            int row = m0 + i * 16 + kh * 4 + r;
            int b_ = row >> 12, t = row & 4095;
            size_t addr = (((size_t)(b_ * NH + hj) * 256 + (t >> 4)) << 10)
                          + (size_t)(dbase + r16) * 16 + (t & 15);
            vtb[addr] = f2bf(acc[i][j][r] + bv);
          }
        }
      }
    }
  } else {
    float* O = (float*)outp;
#pragma unroll
    for (int i = 0; i < MI; i++) {
#pragma unroll
      for (int r = 0; r < 4; r++) {
        int row = m0 + i * 16 + kh * 4 + r;
        float* orow = O + (size_t)row * DMODEL;
#pragma unroll
        for (int j = 0; j < 4; j++) {
          int col = (int)bn0 + wn * 64 + j * 16 + r16;
          orow[col] = acc[i][j][r] + bias0[col];
        }
      }
    }
  }
}

// ---------------- MFMA banded local attention ----------------
// 64 queries/block (4 waves x 16 queries). Q,K row-major [8192][768];
// V block-transposed [bh][tb][d][tl]. Per wave: 6 MFMA scores (16x48),
// masked softmax (intra-quad shfl reductions), P -> LDS (C-layout -> A-layout),
// 8 MFMA PV with V B-frags read directly from global. Out bf16 [8192][768].
#define PSS 72   // Ps row stride (u16): 144B, 16B-aligned, 2-way banks (free)

__global__ __launch_bounds__(256)
void attn_mfma(const u16* __restrict__ qkv, const u16* __restrict__ vt,
               u16* __restrict__ attn) {
  __shared__ __align__(16) u16 Ps[4][16 * PSS];   // 9216 B
  const int tid = threadIdx.x, lane = tid & 63, wave = tid >> 6;
  const int r16 = lane & 15, quad = lane >> 4;
  const int q0 = blockIdx.x * 64;
  const int h = blockIdx.y, b = blockIdx.z;
  const long rowbase = (long)b * T_LEN;
  const int hc = h * HD;
  const u16* Qg = qkv;
  const u16* Kg = qkv + QKV_STRIDE;
  const u16* Vh = vt + ((size_t)(b * NH + h)) * (256 * 1024);

  const int qbase = q0 + wave * 16;   // first query of this wave
  const int kb = qbase - 16;          // first key (mult of 16, may be <0)

  // Q A-frags: rows qbase+r16, dims quad*8 (+0 / +32)
  const u16* qrow = Qg + (rowbase + qbase + r16) * DMODEL + hc + quad * 8;
  bf16x8 qa0 = *(const bf16x8*)qrow;
  bf16x8 qa1 = *(const bf16x8*)(qrow + 32);

  // scores: 3 key tiles x (K=64 -> 2 mfma)
  f32x4 s[3];
#pragma unroll
  for (int t = 0; t < 3; t++) {
    const u16* krow = Kg + (rowbase + kb + t * 16 + r16) * DMODEL + hc + quad * 8;
    bf16x8 kf0 = *(const bf16x8*)krow;
    bf16x8 kf1 = *(const bf16x8*)(krow + 32);
    f32x4 a = {};
    a = __builtin_amdgcn_mfma_f32_16x16x32_bf16(qa0, kf0, a, 0, 0, 0);
    a = __builtin_amdgcn_mfma_f32_16x16x32_bf16(qa1, kf1, a, 0, 0, 0);
    s[t] = a;
  }

  // masked softmax per C-row (query = qbase + quad*4 + r), cols across quad lanes
  float pr[3][4];
#pragma unroll
  for (int r = 0; r < 4; r++) {
    const int qg = qbase + quad * 4 + r;
    float sc[3];
#pragma unroll
    for (int t = 0; t < 3; t++) {
      int key = kb + t * 16 + r16;
      bool ok = (key >= qg - 16) && (key <= qg + 16) && (key >= 0) && (key < T_LEN);
      sc[t] = ok ? s[t][r] * 0.125f : -INFINITY;
    }
    float mx = fmaxf(sc[0], fmaxf(sc[1], sc[2]));
    mx = fmaxf(mx, __shfl_xor(mx, 1));
    mx = fmaxf(mx, __shfl_xor(mx, 2));
    mx = fmaxf(mx, __shfl_xor(mx, 4));
    mx = fmaxf(mx, __shfl_xor(mx, 8));
    float e0 = __expf(sc[0] - mx), e1 = __expf(sc[1] - mx), e2 = __expf(sc[2] - mx);
    float l = e0 + e1 + e2;
    l += __shfl_xor(l, 1);
    l += __shfl_xor(l, 2);
    l += __shfl_xor(l, 4);
    l += __shfl_xor(l, 8);
    float inv = 1.0f / l;
    pr[0][r] = e0 * inv; pr[1][r] = e1 * inv; pr[2][r] = e2 * inv;
  }

  // P: C-layout -> LDS (rows=query, cols=key rel kb), zero pad cols 48..63
  u16* psw = &Ps[wave][0];
#pragma unroll
  for (int t = 0; t < 3; t++)
#pragma unroll
    for (int r = 0; r < 4; r++)
      psw[(quad * 4 + r) * PSS + t * 16 + r16] = f2bf(pr[t][r]);
#pragma unroll
  for (int r = 0; r < 4; r++)
    psw[(quad * 4 + r) * PSS + 48 + r16] = 0;

  // P A-frags (keys 0..31, 32..47+pad)
  bf16x8 pa0 = *(const bf16x8*)&psw[r16 * PSS + quad * 8];
  bf16x8 pa1 = *(const bf16x8*)&psw[r16 * PSS + 32 + quad * 8];

  // PV: 4 d-col tiles x 2 k-frags; V B-frags direct from transposed global
  const int kq1 = kb + quad * 8;
  const int kq2 = kb + 32 + quad * 8;
  const int o1 = (kq1 >> 4) * 1024 + (kq1 & 15);
  const int o2 = (kq2 >> 4) * 1024 + (kq2 & 15);
  f32x4 o[4];
#pragma unroll
  for (int c = 0; c < 4; c++) {
    const u16* vb = Vh + (16 * c + r16) * 16;
    bf16x8 v1 = *(const bf16x8*)(vb + o1);
    bf16x8 v2 = *(const bf16x8*)(vb + o2);
    f32x4 a = {};
    a = __builtin_amdgcn_mfma_f32_16x16x32_bf16(pa0, v1, a, 0, 0, 0);
    a = __builtin_amdgcn_mfma_f32_16x16x32_bf16(pa1, v2, a, 0, 0, 0);
    o[c] = a;
  }

  // store O (C-layout): query = qbase+quad*4+r, d = 16c+r16
#pragma unroll
  for (int c = 0; c < 4; c++) {
#pragma unroll
    for (int r = 0; r < 4; r++) {
      int qg = qbase + quad * 4 + r;
      attn[(rowbase + qg) * DMODEL + hc + 16 * c + r16] = f2bf(o[c][r]);
    }
  }
}

// ---------------- launch ----------------
extern "C" void kernel_launch(void* const* d_in, const int* in_sizes, int n_in,
                              void* d_out, int out_size, void* d_ws, size_t ws_size,
                              hipStream_t stream) {
  const float* x  = (const float*)d_in[0];
  const float* Wq = (const float*)d_in[1];
  const float* bq = (const float*)d_in[2];
  const float* Wk = (const float*)d_in[3];
  const float* bk = (const float*)d_in[4];
  const float* Wv = (const float*)d_in[5];
  const float* bv = (const float*)d_in[6];
  const float* Wo = (const float*)d_in[7];
  const float* bo = (const float*)d_in[8];
  float* out = (float*)d_out;
  char* ws = (char*)d_ws;

  u16* xb   = (u16*)(ws);                 // 8192*768 bf16
  u16* wqkv = (u16*)(ws + 12582912);      // 2304*768 bf16
  u16* wo_b = (u16*)(ws + 16121856);      // 768*768 bf16
  u16* qkv  = (u16*)(ws + 17301504);      // 3*6291456 bf16 (Q,K row-major; V transposed)
  u16* attn = (u16*)(ws + 55050240);      // 8192*768 bf16

  cvt_all<<<8448, 256, 0, stream>>>(x, Wq, Wk, Wv, Wo, xb, wqkv, wo_b);

  gemm_bt<0, 4><<<dim3(64, 18), 256, 0, stream>>>(xb, wqkv, bq, bk, bv, (void*)qkv);
  attn_mfma<<<dim3(64, 12, 2), 256, 0, stream>>>(qkv, qkv + 2 * QKV_STRIDE, attn);
  gemm_bt<1, 2><<<dim3(128, 6), 256, 0, stream>>>(attn, wo_b, bo, bo, bo, (void*)out);
}

// Round 7
// 176.164 us; speedup vs baseline: 1.2485x; 1.0069x over previous
//
#include <hip/hip_runtime.h>
#include <math.h>
#include <cstdint>
#include <cstddef>

typedef unsigned short u16;
typedef short bf16x8 __attribute__((ext_vector_type(8)));
typedef float f32x4 __attribute__((ext_vector_type(4)));
typedef u16 u16x8 __attribute__((ext_vector_type(8)));
typedef u16 u16x4 __attribute__((ext_vector_type(4)));

#define T_LEN 4096
#define NH 12
#define HD 64
#define DMODEL 768
#define GK 768                    // K dim for both GEMMs
#define QKV_STRIDE 6291456ul      // elems per q/k/v tensor = 8192*768

__device__ __forceinline__ u16 f2bf(float x) {
  union { float f; unsigned u; } v; v.f = x;
  unsigned r = v.u + 0x7fffu + ((v.u >> 16) & 1u);
  return (u16)(r >> 16);
}

__device__ __forceinline__ void async16(const u16* g, u16* l) {
  __builtin_amdgcn_global_load_lds(
      (const __attribute__((address_space(1))) unsigned int*)g,
      (__attribute__((address_space(3))) unsigned int*)l, 16, 0, 0);
}

// ---------------- fused fp32 -> bf16 conversion (x + 4 weights, one launch) ----------------
__global__ void cvt_all(const float* __restrict__ x,
                        const float* __restrict__ Wq, const float* __restrict__ Wk,
                        const float* __restrict__ Wv, const float* __restrict__ Wo,
                        u16* __restrict__ xb, u16* __restrict__ wqkv, u16* __restrict__ wo_b) {
  int bx = blockIdx.x;
  const float* s; u16* d; int base;
  if (bx < 6144)      { s = x;  d = xb;             base = bx; }
  else if (bx < 6720) { s = Wq; d = wqkv;           base = bx - 6144; }
  else if (bx < 7296) { s = Wk; d = wqkv + 589824;  base = bx - 6720; }
  else if (bx < 7872) { s = Wv; d = wqkv + 1179648; base = bx - 7296; }
  else                { s = Wo; d = wo_b;           base = bx - 7872; }
  int i = (base * 256 + (int)threadIdx.x) * 4;
  float4 v = *(const float4*)(s + i);
  u16x4 o;
  o[0] = f2bf(v.x); o[1] = f2bf(v.y); o[2] = f2bf(v.z); o[3] = f2bf(v.w);
  *(u16x4*)(d + i) = o;
}

// ---------------- GEMM: C = A[M,K] * B[N,K]^T + bias ----------------
// Tile BMt x 128 (BMt = MI*32), BK=32, 256 threads (4 waves 2x2), 16x16x32 bf16 MFMA.
// XOR chunk swizzle on LDS tiles (conflict-free frag reads).
// EPI=0: bf16 out. Q,K tensors row-major [8192,768]; V tensor written
//        block-transposed: V[b*12+h][t/16][d(64)][t%16] (for MFMA attention B-frags).
//        V addressing decomposes: t>>4 = m0/16+i, t&15 = kh*4+r -> contiguous r,
//        wave covers 512B contiguous per (j,i): coalesced u16x4 stores.
// EPI=1: fp32 direct store [8192,768] (+bias0)
#define BN 128
#define BK 32

template <int EPI, int MI>
__global__ __launch_bounds__(256)
void gemm_bt(const u16* __restrict__ A, const u16* __restrict__ B,
             const float* __restrict__ bias0, const float* __restrict__ bias1,
             const float* __restrict__ bias2, void* __restrict__ outp) {
  constexpr int BMt = MI * 32;
  __shared__ __align__(16) u16 As[BMt * BK];
  __shared__ __align__(16) u16 Bs[BN * BK];

  const int tid  = threadIdx.x;
  const int lane = tid & 63;
  const int wave = tid >> 6;
  const int wm = wave & 1, wn = wave >> 1;
  const long am0 = (long)blockIdx.x * BMt;
  const long bn0 = (long)blockIdx.y * BN;
  const int r16 = lane & 15;
  const int kh  = lane >> 4;
  const int sw8 = (kh ^ ((r16 >> 1) & 3)) * 8;   // swizzled chunk offset for frag reads

  f32x4 acc[MI][4] = {};

  // staging: lane l -> row l>>2, global chunk (l&3)^((l>>3)&3); LDS dest lane-linear
  const int srow   = lane >> 2;
  const int schunk = ((lane & 3) ^ ((lane >> 3) & 3)) * 8;
  const u16* Ag = A + (am0 + wave * 16 + srow) * GK + schunk;
  const u16* Bg = B + (bn0 + wave * 16 + srow) * GK + schunk;
  u16* Bl0 = &Bs[(wave * 16) * BK];
  u16* Bl1 = &Bs[(64 + wave * 16) * BK];

  for (int kt = 0; kt < GK; kt += BK) {
    __syncthreads();
#pragma unroll
    for (int s = 0; s < MI / 2; s++)
      async16(Ag + (size_t)(s * 64) * GK + kt, &As[(s * 64 + wave * 16) * BK]);
    async16(Bg + kt, Bl0);
    async16(Bg + 64 * GK + kt, Bl1);
    __syncthreads();
    bf16x8 af[MI], bfr[4];
#pragma unroll
    for (int i = 0; i < MI; i++)
      af[i] = *(const bf16x8*)&As[(wm * MI * 16 + i * 16 + r16) * BK + sw8];
#pragma unroll
    for (int j = 0; j < 4; j++)
      bfr[j] = *(const bf16x8*)&Bs[(wn * 64 + j * 16 + r16) * BK + sw8];
#pragma unroll
    for (int i = 0; i < MI; i++)
#pragma unroll
      for (int j = 0; j < 4; j++)
        acc[i][j] = __builtin_amdgcn_mfma_f32_16x16x32_bf16(af[i], bfr[j], acc[i][j], 0, 0, 0);
  }

  const int m0 = (int)am0 + wm * MI * 16;   // global row base of this wave's subtile

  if (EPI == 0) {
    const int tens = (int)(bn0 / 768);
    const int c0 = (int)bn0 - tens * 768;
    const float* bp = (tens == 0) ? bias0 : ((tens == 1) ? bias1 : bias2);
    if (tens < 2) {
      // Q or K: row-major [8192][768]
      u16* outb = (u16*)outp + (size_t)tens * QKV_STRIDE;
#pragma unroll
      for (int j = 0; j < 4; j++) {
        int col = c0 + wn * 64 + j * 16 + r16;
        float bv = bp[col];
#pragma unroll
        for (int i = 0; i < MI; i++) {
          u16* p0 = outb + (size_t)(m0 + i * 16 + kh * 4) * DMODEL + col;
#pragma unroll
          for (int r = 0; r < 4; r++)
            p0[r * DMODEL] = f2bf(acc[i][j][r] + bv);
        }
      }
    } else {
      // V: block-transposed [b*12+h][t>>4][d][t&15]; per (j,i) the wave writes
      // 512B contiguous (lane offset (dbase+r16)*16 + kh*4, r contiguous).
      u16* vtb = (u16*)outp + 2 * QKV_STRIDE;
      const int kr = kh * 4;
#pragma unroll
      for (int j = 0; j < 4; j++) {
        int cl = c0 + wn * 64 + j * 16;      // multiple of 16, lane-uniform
        int hj = cl >> 6;
        int dlane = (cl & 63) + r16;
        float bv = bp[cl + r16];
#pragma unroll
        for (int i = 0; i < MI; i++) {
          int row0 = m0 + i * 16;
          int b_ = row0 >> 12;
          int tb = (row0 & 4095) >> 4;
          size_t base = (((size_t)(b_ * NH + hj) * 256 + tb) << 10) + dlane * 16 + kr;
          u16x4 pk;
#pragma unroll
          for (int r = 0; r < 4; r++) pk[r] = f2bf(acc[i][j][r] + bv);
          *(u16x4*)(vtb + base) = pk;
        }
      }
    }
  } else {
    float* O = (float*)outp;
#pragma unroll
    for (int i = 0; i < MI; i++) {
#pragma unroll
      for (int r = 0; r < 4; r++) {
        int row = m0 + i * 16 + kh * 4 + r;
        float* orow = O + (size_t)row * DMODEL;
#pragma unroll
        for (int j = 0; j < 4; j++) {
          int col = (int)bn0 + wn * 64 + j * 16 + r16;
          orow[col] = acc[i][j][r] + bias0[col];
        }
      }
    }
  }
}

// ---------------- MFMA banded local attention ----------------
// 64 queries/block (4 waves x 16 queries). Q,K row-major [8192][768];
// V block-transposed [bh][tb][d][tl]. Per wave: 6 MFMA scores (16x48),
// masked softmax (intra-quad shfl reductions), P -> LDS (C-layout -> A-layout),
// 8 MFMA PV with V B-frags read directly from global. Out bf16 [8192][768].
#define PSS 72   // Ps row stride (u16): 144B, 16B-aligned, 2-way banks (free)

__global__ __launch_bounds__(256)
void attn_mfma(const u16* __restrict__ qkv, const u16* __restrict__ vt,
               u16* __restrict__ attn) {
  __shared__ __align__(16) u16 Ps[4][16 * PSS];   // 9216 B
  const int tid = threadIdx.x, lane = tid & 63, wave = tid >> 6;
  const int r16 = lane & 15, quad = lane >> 4;
  const int q0 = blockIdx.x * 64;
  const int h = blockIdx.y, b = blockIdx.z;
  const long rowbase = (long)b * T_LEN;
  const int hc = h * HD;
  const u16* Qg = qkv;
  const u16* Kg = qkv + QKV_STRIDE;
  const u16* Vh = vt + ((size_t)(b * NH + h)) * (256 * 1024);

  const int qbase = q0 + wave * 16;   // first query of this wave
  const int kb = qbase - 16;          // first key (mult of 16, may be <0)

  // Q A-frags: rows qbase+r16, dims quad*8 (+0 / +32)
  const u16* qrow = Qg + (rowbase + qbase + r16) * DMODEL + hc + quad * 8;
  bf16x8 qa0 = *(const bf16x8*)qrow;
  bf16x8 qa1 = *(const bf16x8*)(qrow + 32);

  // scores: 3 key tiles x (K=64 -> 2 mfma)
  f32x4 s[3];
#pragma unroll
  for (int t = 0; t < 3; t++) {
    const u16* krow = Kg + (rowbase + kb + t * 16 + r16) * DMODEL + hc + quad * 8;
    bf16x8 kf0 = *(const bf16x8*)krow;
    bf16x8 kf1 = *(const bf16x8*)(krow + 32);
    f32x4 a = {};
    a = __builtin_amdgcn_mfma_f32_16x16x32_bf16(qa0, kf0, a, 0, 0, 0);
    a = __builtin_amdgcn_mfma_f32_16x16x32_bf16(qa1, kf1, a, 0, 0, 0);
    s[t] = a;
  }

  // masked softmax per C-row (query = qbase + quad*4 + r), cols across quad lanes
  float pr[3][4];
#pragma unroll
  for (int r = 0; r < 4; r++) {
    const int qg = qbase + quad * 4 + r;
    float sc[3];
#pragma unroll
    for (int t = 0; t < 3; t++) {
      int key = kb + t * 16 + r16;
      bool ok = (key >= qg - 16) && (key <= qg + 16) && (key >= 0) && (key < T_LEN);
      sc[t] = ok ? s[t][r] * 0.125f : -INFINITY;
    }
    float mx = fmaxf(sc[0], fmaxf(sc[1], sc[2]));
    mx = fmaxf(mx, __shfl_xor(mx, 1));
    mx = fmaxf(mx, __shfl_xor(mx, 2));
    mx = fmaxf(mx, __shfl_xor(mx, 4));
    mx = fmaxf(mx, __shfl_xor(mx, 8));
    float e0 = __expf(sc[0] - mx), e1 = __expf(sc[1] - mx), e2 = __expf(sc[2] - mx);
    float l = e0 + e1 + e2;
    l += __shfl_xor(l, 1);
    l += __shfl_xor(l, 2);
    l += __shfl_xor(l, 4);
    l += __shfl_xor(l, 8);
    float inv = 1.0f / l;
    pr[0][r] = e0 * inv; pr[1][r] = e1 * inv; pr[2][r] = e2 * inv;
  }

  // P: C-layout -> LDS (rows=query, cols=key rel kb), zero pad cols 48..63
  u16* psw = &Ps[wave][0];
#pragma unroll
  for (int t = 0; t < 3; t++)
#pragma unroll
    for (int r = 0; r < 4; r++)
      psw[(quad * 4 + r) * PSS + t * 16 + r16] = f2bf(pr[t][r]);
#pragma unroll
  for (int r = 0; r < 4; r++)
    psw[(quad * 4 + r) * PSS + 48 + r16] = 0;

  // P A-frags (keys 0..31, 32..47+pad)
  bf16x8 pa0 = *(const bf16x8*)&psw[r16 * PSS + quad * 8];
  bf16x8 pa1 = *(const bf16x8*)&psw[r16 * PSS + 32 + quad * 8];

  // PV: 4 d-col tiles x 2 k-frags; V B-frags direct from transposed global
  const int kq1 = kb + quad * 8;
  const int kq2 = kb + 32 + quad * 8;
  const int o1 = (kq1 >> 4) * 1024 + (kq1 & 15);
  const int o2 = (kq2 >> 4) * 1024 + (kq2 & 15);
  f32x4 o[4];
#pragma unroll
  for (int c = 0; c < 4; c++) {
    const u16* vb = Vh + (16 * c + r16) * 16;
    bf16x8 v1 = *(const bf16x8*)(vb + o1);
    bf16x8 v2 = *(const bf16x8*)(vb + o2);
    f32x4 a = {};
    a = __builtin_amdgcn_mfma_f32_16x16x32_bf16(pa0, v1, a, 0, 0, 0);
    a = __builtin_amdgcn_mfma_f32_16x16x32_bf16(pa1, v2, a, 0, 0, 0);
    o[c] = a;
  }

  // store O (C-layout): query = qbase+quad*4+r, d = 16c+r16
#pragma unroll
  for (int c = 0; c < 4; c++) {
#pragma unroll
    for (int r = 0; r < 4; r++) {
      int qg = qbase + quad * 4 + r;
      attn[(rowbase + qg) * DMODEL + hc + 16 * c + r16] = f2bf(o[c][r]);
    }
  }
}

// ---------------- launch ----------------
extern "C" void kernel_launch(void* const* d_in, const int* in_sizes, int n_in,
                              void* d_out, int out_size, void* d_ws, size_t ws_size,
                              hipStream_t stream) {
  const float* x  = (const float*)d_in[0];
  const float* Wq = (const float*)d_in[1];
  const float* bq = (const float*)d_in[2];
  const float* Wk = (const float*)d_in[3];
  const float* bk = (const float*)d_in[4];
  const float* Wv = (const float*)d_in[5];
  const float* bv = (const float*)d_in[6];
  const float* Wo = (const float*)d_in[7];
  const float* bo = (const float*)d_in[8];
  float* out = (float*)d_out;
  char* ws = (char*)d_ws;

  u16* xb   = (u16*)(ws);                 // 8192*768 bf16
  u16* wqkv = (u16*)(ws + 12582912);      // 2304*768 bf16
  u16* wo_b = (u16*)(ws + 16121856);      // 768*768 bf16
  u16* qkv  = (u16*)(ws + 17301504);      // 3*6291456 bf16 (Q,K row-major; V transposed)
  u16* attn = (u16*)(ws + 55050240);      // 8192*768 bf16

  cvt_all<<<8448, 256, 0, stream>>>(x, Wq, Wk, Wv, Wo, xb, wqkv, wo_b);

  gemm_bt<0, 4><<<dim3(64, 18), 256, 0, stream>>>(xb, wqkv, bq, bk, bv, (void*)qkv);
  attn_mfma<<<dim3(64, 12, 2), 256, 0, stream>>>(qkv, qkv + 2 * QKV_STRIDE, attn);
  gemm_bt<1, 2><<<dim3(128, 6), 256, 0, stream>>>(attn, wo_b, bo, bo, bo, (void*)out);
}

// Round 8
// 171.252 us; speedup vs baseline: 1.2843x; 1.0287x over previous
//
#include <hip/hip_runtime.h>
#include <math.h>
#include <cstdint>
#include <cstddef>

typedef unsigned short u16;
typedef short bf16x8 __attribute__((ext_vector_type(8)));
typedef float f32x4 __attribute__((ext_vector_type(4)));
typedef u16 u16x8 __attribute__((ext_vector_type(8)));
typedef u16 u16x4 __attribute__((ext_vector_type(4)));

#define T_LEN 4096
#define NH 12
#define HD 64
#define DMODEL 768
#define GK 768                    // K dim for both GEMMs
#define QKV_STRIDE 6291456ul      // elems per q/k/v tensor = 8192*768

__device__ __forceinline__ u16 f2bf(float x) {
  union { float f; unsigned u; } v; v.f = x;
  unsigned r = v.u + 0x7fffu + ((v.u >> 16) & 1u);
  return (u16)(r >> 16);
}

__device__ __forceinline__ void async16(const u16* g, u16* l) {
  __builtin_amdgcn_global_load_lds(
      (const __attribute__((address_space(1))) unsigned int*)g,
      (__attribute__((address_space(3))) unsigned int*)l, 16, 0, 0);
}

// ---------------- fused fp32 -> bf16 conversion (x + 4 weights, one launch) ----------------
__global__ void cvt_all(const float* __restrict__ x,
                        const float* __restrict__ Wq, const float* __restrict__ Wk,
                        const float* __restrict__ Wv, const float* __restrict__ Wo,
                        u16* __restrict__ xb, u16* __restrict__ wqkv, u16* __restrict__ wo_b) {
  int bx = blockIdx.x;
  const float* s; u16* d; int base;
  if (bx < 6144)      { s = x;  d = xb;             base = bx; }
  else if (bx < 6720) { s = Wq; d = wqkv;           base = bx - 6144; }
  else if (bx < 7296) { s = Wk; d = wqkv + 589824;  base = bx - 6720; }
  else if (bx < 7872) { s = Wv; d = wqkv + 1179648; base = bx - 7296; }
  else                { s = Wo; d = wo_b;           base = bx - 7872; }
  int i = (base * 256 + (int)threadIdx.x) * 4;
  float4 v = *(const float4*)(s + i);
  u16x4 o;
  o[0] = f2bf(v.x); o[1] = f2bf(v.y); o[2] = f2bf(v.z); o[3] = f2bf(v.w);
  *(u16x4*)(d + i) = o;
}

// ---------------- GEMM: C = A[M,K] * B[N,K]^T + bias ----------------
// Tile BMt x 128 (BMt = MI*32), BK=32, 256 threads (4 waves 2x2), 16x16x32 bf16 MFMA.
// XOR chunk swizzle on LDS tiles (conflict-free frag reads).
// EPI=0: Q/K bf16 row-major [8192,768] x2 tensors (bias0/bias1 select by bn0)
// EPI=1: fp32 direct store [8192,768] (+bias0)
// EPI=2: V bf16 block-transposed [b*12+h][t>>4][d][t&15]; per (j,i) the wave
//        writes 512B contiguous (coalesced u16x4 stores).
#define BN 128
#define BK 32

template <int EPI, int MI>
__global__ __launch_bounds__(256)
void gemm_bt(const u16* __restrict__ A, const u16* __restrict__ B,
             const float* __restrict__ bias0, const float* __restrict__ bias1,
             void* __restrict__ outp) {
  constexpr int BMt = MI * 32;
  __shared__ __align__(16) u16 As[BMt * BK];
  __shared__ __align__(16) u16 Bs[BN * BK];

  const int tid  = threadIdx.x;
  const int lane = tid & 63;
  const int wave = tid >> 6;
  const int wm = wave & 1, wn = wave >> 1;
  const long am0 = (long)blockIdx.x * BMt;
  const long bn0 = (long)blockIdx.y * BN;
  const int r16 = lane & 15;
  const int kh  = lane >> 4;
  const int sw8 = (kh ^ ((r16 >> 1) & 3)) * 8;   // swizzled chunk offset for frag reads

  f32x4 acc[MI][4] = {};

  // staging: lane l -> row l>>2, global chunk (l&3)^((l>>3)&3); LDS dest lane-linear
  const int srow   = lane >> 2;
  const int schunk = ((lane & 3) ^ ((lane >> 3) & 3)) * 8;
  const u16* Ag = A + (am0 + wave * 16 + srow) * GK + schunk;
  const u16* Bg = B + (bn0 + wave * 16 + srow) * GK + schunk;
  u16* Bl0 = &Bs[(wave * 16) * BK];
  u16* Bl1 = &Bs[(64 + wave * 16) * BK];

  for (int kt = 0; kt < GK; kt += BK) {
    __syncthreads();
#pragma unroll
    for (int s = 0; s < MI / 2; s++)
      async16(Ag + (size_t)(s * 64) * GK + kt, &As[(s * 64 + wave * 16) * BK]);
    async16(Bg + kt, Bl0);
    async16(Bg + 64 * GK + kt, Bl1);
    __syncthreads();
    bf16x8 af[MI], bfr[4];
#pragma unroll
    for (int i = 0; i < MI; i++)
      af[i] = *(const bf16x8*)&As[(wm * MI * 16 + i * 16 + r16) * BK + sw8];
#pragma unroll
    for (int j = 0; j < 4; j++)
      bfr[j] = *(const bf16x8*)&Bs[(wn * 64 + j * 16 + r16) * BK + sw8];
#pragma unroll
    for (int i = 0; i < MI; i++)
#pragma unroll
      for (int j = 0; j < 4; j++)
        acc[i][j] = __builtin_amdgcn_mfma_f32_16x16x32_bf16(af[i], bfr[j], acc[i][j], 0, 0, 0);
  }

  const int m0 = (int)am0 + wm * MI * 16;   // global row base of this wave's subtile

  if (EPI == 0) {
    // Q or K: row-major [8192][768], tensor selected by bn0
    const int tens = (int)(bn0 >= 768);
    const int c0 = (int)bn0 - tens * 768;
    const float* bp = tens ? bias1 : bias0;
    u16* outb = (u16*)outp + (size_t)tens * QKV_STRIDE;
#pragma unroll
    for (int j = 0; j < 4; j++) {
      int col = c0 + wn * 64 + j * 16 + r16;
      float bv = bp[col];
#pragma unroll
      for (int i = 0; i < MI; i++) {
#pragma unroll
        for (int r = 0; r < 4; r++) {
          int row = m0 + i * 16 + kh * 4 + r;
          outb[(size_t)row * DMODEL + col] = f2bf(acc[i][j][r] + bv);
        }
      }
    }
  } else if (EPI == 2) {
    // V: block-transposed [b*12+h][t>>4][d][t&15]
    u16* vtb = (u16*)outp;
    const int kr = kh * 4;
#pragma unroll
    for (int j = 0; j < 4; j++) {
      int cl = (int)bn0 + wn * 64 + j * 16;   // multiple of 16, lane-uniform
      int hj = cl >> 6;
      int dlane = (cl & 63) + r16;
      float bv = bias0[cl + r16];
#pragma unroll
      for (int i = 0; i < MI; i++) {
        int row0 = m0 + i * 16;
        int b_ = row0 >> 12;
        int tb = (row0 & 4095) >> 4;
        size_t base = (((size_t)(b_ * NH + hj) * 256 + tb) << 10) + dlane * 16 + kr;
        u16x4 pk;
#pragma unroll
        for (int r = 0; r < 4; r++) pk[r] = f2bf(acc[i][j][r] + bv);
        *(u16x4*)(vtb + base) = pk;
      }
    }
  } else {
    float* O = (float*)outp;
#pragma unroll
    for (int i = 0; i < MI; i++) {
#pragma unroll
      for (int r = 0; r < 4; r++) {
        int row = m0 + i * 16 + kh * 4 + r;
        float* orow = O + (size_t)row * DMODEL;
#pragma unroll
        for (int j = 0; j < 4; j++) {
          int col = (int)bn0 + wn * 64 + j * 16 + r16;
          orow[col] = acc[i][j][r] + bias0[col];
        }
      }
    }
  }
}

// ---------------- MFMA banded local attention ----------------
// 64 queries/block (4 waves x 16 queries). Q,K row-major [8192][768];
// V block-transposed [bh][tb][d][tl]. Per wave: 6 MFMA scores (16x48),
// masked softmax (intra-quad shfl reductions), P -> LDS (C-layout -> A-layout),
// 8 MFMA PV with V B-frags read directly from global. Out bf16 [8192][768].
#define PSS 72   // Ps row stride (u16): 144B, 16B-aligned, 2-way banks (free)

__global__ __launch_bounds__(256)
void attn_mfma(const u16* __restrict__ qkv, const u16* __restrict__ vt,
               u16* __restrict__ attn) {
  __shared__ __align__(16) u16 Ps[4][16 * PSS];   // 9216 B
  const int tid = threadIdx.x, lane = tid & 63, wave = tid >> 6;
  const int r16 = lane & 15, quad = lane >> 4;
  const int q0 = blockIdx.x * 64;
  const int h = blockIdx.y, b = blockIdx.z;
  const long rowbase = (long)b * T_LEN;
  const int hc = h * HD;
  const u16* Qg = qkv;
  const u16* Kg = qkv + QKV_STRIDE;
  const u16* Vh = vt + ((size_t)(b * NH + h)) * (256 * 1024);

  const int qbase = q0 + wave * 16;   // first query of this wave
  const int kb = qbase - 16;          // first key (mult of 16, may be <0)

  // Q A-frags: rows qbase+r16, dims quad*8 (+0 / +32)
  const u16* qrow = Qg + (rowbase + qbase + r16) * DMODEL + hc + quad * 8;
  bf16x8 qa0 = *(const bf16x8*)qrow;
  bf16x8 qa1 = *(const bf16x8*)(qrow + 32);

  // scores: 3 key tiles x (K=64 -> 2 mfma)
  f32x4 s[3];
#pragma unroll
  for (int t = 0; t < 3; t++) {
    const u16* krow = Kg + (rowbase + kb + t * 16 + r16) * DMODEL + hc + quad * 8;
    bf16x8 kf0 = *(const bf16x8*)krow;
    bf16x8 kf1 = *(const bf16x8*)(krow + 32);
    f32x4 a = {};
    a = __builtin_amdgcn_mfma_f32_16x16x32_bf16(qa0, kf0, a, 0, 0, 0);
    a = __builtin_amdgcn_mfma_f32_16x16x32_bf16(qa1, kf1, a, 0, 0, 0);
    s[t] = a;
  }

  // masked softmax per C-row (query = qbase + quad*4 + r), cols across quad lanes
  float pr[3][4];
#pragma unroll
  for (int r = 0; r < 4; r++) {
    const int qg = qbase + quad * 4 + r;
    float sc[3];
#pragma unroll
    for (int t = 0; t < 3; t++) {
      int key = kb + t * 16 + r16;
      bool ok = (key >= qg - 16) && (key <= qg + 16) && (key >= 0) && (key < T_LEN);
      sc[t] = ok ? s[t][r] * 0.125f : -INFINITY;
    }
    float mx = fmaxf(sc[0], fmaxf(sc[1], sc[2]));
    mx = fmaxf(mx, __shfl_xor(mx, 1));
    mx = fmaxf(mx, __shfl_xor(mx, 2));
    mx = fmaxf(mx, __shfl_xor(mx, 4));
    mx = fmaxf(mx, __shfl_xor(mx, 8));
    float e0 = __expf(sc[0] - mx), e1 = __expf(sc[1] - mx), e2 = __expf(sc[2] - mx);
    float l = e0 + e1 + e2;
    l += __shfl_xor(l, 1);
    l += __shfl_xor(l, 2);
    l += __shfl_xor(l, 4);
    l += __shfl_xor(l, 8);
    float inv = 1.0f / l;
    pr[0][r] = e0 * inv; pr[1][r] = e1 * inv; pr[2][r] = e2 * inv;
  }

  // P: C-layout -> LDS (rows=query, cols=key rel kb), zero pad cols 48..63
  u16* psw = &Ps[wave][0];
#pragma unroll
  for (int t = 0; t < 3; t++)
#pragma unroll
    for (int r = 0; r < 4; r++)
      psw[(quad * 4 + r) * PSS + t * 16 + r16] = f2bf(pr[t][r]);
#pragma unroll
  for (int r = 0; r < 4; r++)
    psw[(quad * 4 + r) * PSS + 48 + r16] = 0;

  // P A-frags (keys 0..31, 32..47+pad)
  bf16x8 pa0 = *(const bf16x8*)&psw[r16 * PSS + quad * 8];
  bf16x8 pa1 = *(const bf16x8*)&psw[r16 * PSS + 32 + quad * 8];

  // PV: 4 d-col tiles x 2 k-frags; V B-frags direct from transposed global
  const int kq1 = kb + quad * 8;
  const int kq2 = kb + 32 + quad * 8;
  const int o1 = (kq1 >> 4) * 1024 + (kq1 & 15);
  const int o2 = (kq2 >> 4) * 1024 + (kq2 & 15);
  f32x4 o[4];
#pragma unroll
  for (int c = 0; c < 4; c++) {
    const u16* vb = Vh + (16 * c + r16) * 16;
    bf16x8 v1 = *(const bf16x8*)(vb + o1);
    bf16x8 v2 = *(const bf16x8*)(vb + o2);
    f32x4 a = {};
    a = __builtin_amdgcn_mfma_f32_16x16x32_bf16(pa0, v1, a, 0, 0, 0);
    a = __builtin_amdgcn_mfma_f32_16x16x32_bf16(pa1, v2, a, 0, 0, 0);
    o[c] = a;
  }

  // store O (C-layout): query = qbase+quad*4+r, d = 16c+r16
#pragma unroll
  for (int c = 0; c < 4; c++) {
#pragma unroll
    for (int r = 0; r < 4; r++) {
      int qg = qbase + quad * 4 + r;
      attn[(rowbase + qg) * DMODEL + hc + 16 * c + r16] = f2bf(o[c][r]);
    }
  }
}

// ---------------- launch ----------------
extern "C" void kernel_launch(void* const* d_in, const int* in_sizes, int n_in,
                              void* d_out, int out_size, void* d_ws, size_t ws_size,
                              hipStream_t stream) {
  const float* x  = (const float*)d_in[0];
  const float* Wq = (const float*)d_in[1];
  const float* bq = (const float*)d_in[2];
  const float* Wk = (const float*)d_in[3];
  const float* bk = (const float*)d_in[4];
  const float* Wv = (const float*)d_in[5];
  const float* bv = (const float*)d_in[6];
  const float* Wo = (const float*)d_in[7];
  const float* bo = (const float*)d_in[8];
  float* out = (float*)d_out;
  char* ws = (char*)d_ws;

  u16* xb   = (u16*)(ws);                 // 8192*768 bf16
  u16* wqkv = (u16*)(ws + 12582912);      // 2304*768 bf16 (Wq,Wk,Wv rows)
  u16* wo_b = (u16*)(ws + 16121856);      // 768*768 bf16
  u16* qkv  = (u16*)(ws + 17301504);      // 3*6291456 bf16 (Q,K row-major; V transposed)
  u16* attnb = (u16*)(ws + 55050240);     // 8192*768 bf16

  cvt_all<<<8448, 256, 0, stream>>>(x, Wq, Wk, Wv, Wo, xb, wqkv, wo_b);

  // Q,K projection (row-major epilogue, low-VGPR)
  gemm_bt<0, 4><<<dim3(64, 12), 256, 0, stream>>>(xb, wqkv, bq, bk, (void*)qkv);
  // V projection (block-transposed epilogue)
  gemm_bt<2, 4><<<dim3(64, 6), 256, 0, stream>>>(xb, wqkv + 1179648, bv, bv,
                                                 (void*)(qkv + 2 * QKV_STRIDE));
  attn_mfma<<<dim3(64, 12, 2), 256, 0, stream>>>(qkv, qkv + 2 * QKV_STRIDE, attnb);
  gemm_bt<1, 2><<<dim3(128, 6), 256, 0, stream>>>(attnb, wo_b, bo, bo, (void*)out);
}